// Round 1
// baseline (746.923 us; speedup 1.0000x reference)
//
#include <hip/hip_runtime.h>
#include <stdint.h>

// Problem constants
#define NB    8192
#define NIN   784
#define NH    1000
#define NHP   1024      // padded hidden (bit-pack alignment)
#define NOUT  10
#define NOUTP 16        // padded out for W2T rows (64B, s_load_dwordx16)
#define NT    100

// d_out layout: [0 .. 8192000)  = spk_rec  (staging: cur2)
//               [8192000 .. )   = mem_rec  (staging: cur1)
// d_ws  layout: [0 .. 104857600)          = packed spikes [NT][NB][32] dwords
//               [104857600 .. +65536)     = W2T [NHP][NOUTP] fp32

// ---------------- K0: transpose+pad W2 -> W2T[h][o] --------------------------
__global__ __launch_bounds__(256) void k_w2t(const float* __restrict__ W2,
                                             float* __restrict__ w2t) {
  int i = blockIdx.x * 256 + threadIdx.x;   // over NHP*NOUTP = 16384
  int h = i >> 4, o = i & 15;
  float v = (h < NH && o < NOUT) ? W2[o * NH + h] : 0.0f;
  w2t[i] = v;
}

// ---------------- K1: cur1 = x @ W1^T + b1 (fp32 tiled GEMM) -----------------
// C written to mem_rec half of d_out, [B][H] row-major.
__global__ __launch_bounds__(256) void k_gemm1(const float* __restrict__ A,
                                               const float* __restrict__ Bw,
                                               const float* __restrict__ bias,
                                               float* __restrict__ C) {
  __shared__ float As[16][68];
  __shared__ float Bs[16][68];
  const int tid = threadIdx.x;
  const int m0 = blockIdx.x << 6;
  const int n0 = blockIdx.y << 6;
  const int lr = tid >> 2;          // 0..63 row within tile
  const int lk = (tid & 3) << 2;    // k offset 0,4,8,12
  const float* aptr = A + (long)(m0 + lr) * NIN + lk;
  int nrow = n0 + lr; if (nrow > NH - 1) nrow = NH - 1;   // clamp (values unused)
  const float* bptr = Bw + (long)nrow * NIN + lk;
  const int ty = tid >> 4;          // 0..15 (m micro)
  const int tx = tid & 15;          // 0..15 (n micro)
  float acc[4][4] = {};
  float4 av = *(const float4*)aptr;
  float4 bv = *(const float4*)bptr;
  for (int kt = 16; kt <= NIN; kt += 16) {
    __syncthreads();
    As[lk + 0][lr] = av.x; As[lk + 1][lr] = av.y;
    As[lk + 2][lr] = av.z; As[lk + 3][lr] = av.w;
    Bs[lk + 0][lr] = bv.x; Bs[lk + 1][lr] = bv.y;
    Bs[lk + 2][lr] = bv.z; Bs[lk + 3][lr] = bv.w;
    __syncthreads();
    if (kt < NIN) {   // prefetch next K-tile before compute
      av = *(const float4*)(aptr + kt);
      bv = *(const float4*)(bptr + kt);
    }
#pragma unroll
    for (int kk = 0; kk < 16; ++kk) {
      float4 a4 = *(const float4*)&As[kk][ty << 2];
      float4 b4 = *(const float4*)&Bs[kk][tx << 2];
#pragma unroll
      for (int i = 0; i < 4; ++i) {
        float am = (i == 0) ? a4.x : (i == 1) ? a4.y : (i == 2) ? a4.z : a4.w;
        acc[i][0] = fmaf(am, b4.x, acc[i][0]);
        acc[i][1] = fmaf(am, b4.y, acc[i][1]);
        acc[i][2] = fmaf(am, b4.z, acc[i][2]);
        acc[i][3] = fmaf(am, b4.w, acc[i][3]);
      }
    }
  }
  const int n = n0 + (tx << 2);
  if (n < NH) {                      // NH%4==0 -> full float4 always valid
    float4 b4 = *(const float4*)(bias + n);
#pragma unroll
    for (int i = 0; i < 4; ++i) {
      long r = m0 + (ty << 2) + i;
      float4 o4;
      o4.x = acc[i][0] + b4.x; o4.y = acc[i][1] + b4.y;
      o4.z = acc[i][2] + b4.z; o4.w = acc[i][3] + b4.w;
      *(float4*)(C + r * NH + n) = o4;
    }
  }
}

// ---------------- K2: LIF1 scan, state in registers, emit packed spikes ------
// block = one batch row; thread owns 4 neurons h = j*256 + tid (j=0..3).
__global__ __launch_bounds__(256) void k_lif1(const float* __restrict__ cur1,
                                              uint32_t* __restrict__ spikes) {
  const int b = blockIdx.x;
  const int tid = threadIdx.x;
  const int lane = tid & 63;
  const int w = tid >> 6;
  float c[4], syn[4], mem[4];
#pragma unroll
  for (int j = 0; j < 4; ++j) {
    int h = (j << 8) + tid;
    c[j] = (h < NH) ? cur1[(long)b * NH + h] : 0.0f;
    syn[j] = 0.0f; mem[j] = 0.0f;
  }
  uint32_t* sp = spikes + (b << 5) + (w << 1);
  for (int t = 0; t < NT; ++t) {
#pragma unroll
    for (int j = 0; j < 4; ++j) {
      syn[j] = fmaf(0.9f, syn[j], c[j]);
      float r = (mem[j] > 1.0f) ? 1.0f : 0.0f;   // reset from PRE-update mem
      mem[j] = fmaf(0.85f, mem[j], syn[j]) - r;
      unsigned long long mk = __ballot(mem[j] > 1.0f);
      if (lane == 0)
        *(uint2*)(sp + (j << 3)) = make_uint2((uint32_t)mk, (uint32_t)(mk >> 32));
    }
    sp += NB * 32;
  }
}

// ---------------- K3: cur2[t][b][o] = b2[o] + sum_h bit*W2[o][h] -------------
// block = 64 rows (one t, 64 consecutive b) x 4 h-quarters (one per wave).
__global__ __launch_bounds__(256) void k_fc2(const uint32_t* __restrict__ spikes,
                                             const float* __restrict__ w2t,
                                             const float* __restrict__ b2,
                                             float* __restrict__ cur2) {
  __shared__ float red[4][64][11];
  const int tid = threadIdx.x;
  const int lane = tid & 63;
  const int w = tid >> 6;
  const int rb = blockIdx.x;          // 12800 = NT * (NB/64)
  const int t = rb >> 7;
  const int b0 = (rb & 127) << 6;
  const uint32_t* sp = spikes + (((long)t * NB + (b0 + lane)) << 5) + (w << 3);
  const int wu = __builtin_amdgcn_readfirstlane(w);   // wave-uniform -> s_load path
  const float* wbase = w2t + (wu << 12);              // wu*256*16
  uint4 ma = *(const uint4*)sp;
  uint4 mb = *(const uint4*)(sp + 4);
  float acc[10] = {0,0,0,0,0,0,0,0,0,0};
#define DO_DWORD(MVAL, D)                                                      \
  {                                                                            \
    const uint32_t m_ = (MVAL);                                                \
    for (int jg = 0; jg < 4; ++jg) {                                           \
      const uint32_t byte_ = (m_ >> (jg << 3)) & 0xffu;                        \
      const float* wp = wbase + ((((D) << 5) + (jg << 3)) << 4);               \
      _Pragma("unroll")                                                        \
      for (int jj = 0; jj < 8; ++jj) {                                         \
        float bf = (float)((byte_ >> jj) & 1u);                                \
        _Pragma("unroll")                                                      \
        for (int o = 0; o < 10; ++o)                                           \
          acc[o] = fmaf(bf, wp[(jj << 4) + o], acc[o]);                        \
      }                                                                        \
    }                                                                          \
  }
  DO_DWORD(ma.x, 0) DO_DWORD(ma.y, 1) DO_DWORD(ma.z, 2) DO_DWORD(ma.w, 3)
  DO_DWORD(mb.x, 4) DO_DWORD(mb.y, 5) DO_DWORD(mb.z, 6) DO_DWORD(mb.w, 7)
#undef DO_DWORD
#pragma unroll
  for (int o = 0; o < 10; ++o) red[w][lane][o] = acc[o];
  __syncthreads();
  const long obase = ((long)t * NB + b0) * NOUT;
  for (int i = tid; i < 640; i += 256) {
    int row = i / 10;
    int o = i - row * 10;
    float s = red[0][row][o] + red[1][row][o] + red[2][row][o] + red[3][row][o]
            + b2[o];
    cur2[obase + i] = s;
  }
}

// ---------------- K4: LIF2 scan + final outputs ------------------------------
// thread = (b,o); reads cur2 in spk half, overwrites with spk, writes mem half.
__global__ __launch_bounds__(256) void k_lif2(float* io) {
  const int gid = blockIdx.x * 256 + threadIdx.x;   // < 81920
  float* sp = io + gid;
  float* mm = io + 8192000 + gid;
  float syn = 0.0f, mem = 0.0f;
#pragma unroll 4
  for (int t = 0; t < NT; ++t) {
    float c = sp[t * 81920];
    syn = fmaf(0.9f, syn, c);
    float r = (mem > 1.0f) ? 1.0f : 0.0f;
    mem = fmaf(0.85f, mem, syn) - r;
    sp[t * 81920] = (mem > 1.0f) ? 1.0f : 0.0f;
    mm[t * 81920] = mem;
  }
}

extern "C" void kernel_launch(void* const* d_in, const int* in_sizes, int n_in,
                              void* d_out, int out_size, void* d_ws, size_t ws_size,
                              hipStream_t stream) {
  const float* x  = (const float*)d_in[0];
  const float* W1 = (const float*)d_in[1];
  const float* b1 = (const float*)d_in[2];
  const float* W2 = (const float*)d_in[3];
  const float* b2 = (const float*)d_in[4];
  float* out = (float*)d_out;
  float* memhalf = out + 8192000;                 // cur1 staging / mem_rec
  uint32_t* spikes = (uint32_t*)d_ws;             // 104857600 B
  float* w2t = (float*)((char*)d_ws + 104857600); // 65536 B

  k_w2t<<<64, 256, 0, stream>>>(W2, w2t);
  dim3 g1(NB / 64, NHP / 64);
  k_gemm1<<<g1, 256, 0, stream>>>(x, W1, b1, memhalf);
  k_lif1<<<NB, 256, 0, stream>>>(memhalf, spikes);
  k_fc2<<<NT * (NB / 64), 256, 0, stream>>>(spikes, w2t, b2, out);
  k_lif2<<<81920 / 256, 256, 0, stream>>>(out);
}

// Round 3
// 572.429 us; speedup vs baseline: 1.3048x; 1.3048x over previous
//
#include <hip/hip_runtime.h>
#include <stdint.h>

// Problem constants
#define NB    8192
#define NIN   784
#define NH    1000
#define NHP   1024      // padded hidden (bit-pack alignment)
#define NOUT  10
#define NOUTP 16        // padded out for W2T rows (64B)
#define NT    100

// d_out layout: [0 .. 8192000)  = spk_rec  (staging: cur2)
//               [8192000 .. )   = mem_rec  (staging: cur1)
// d_ws  layout: [0 .. 104857600)          = packed spikes [NT][NB][32] dwords
//               [104857600 .. +65536)     = W2T [NHP][NOUTP] fp32
//
// packed-spike row layout (32 dwords per (t,b) row):
//   dword index k = w*8 + j*2 + half   (w = lif1 wave 0..3, j = neuron quarter,
//                                       half = low/high 32 lanes)
//   bit l of that dword  <->  h = j*256 + w*64 + half*32 + l

typedef float v2f __attribute__((ext_vector_type(2)));

// ---------------- K0: transpose+pad W2 -> W2T[h][o] --------------------------
__global__ __launch_bounds__(256) void k_w2t(const float* __restrict__ W2,
                                             float* __restrict__ w2t) {
  int i = blockIdx.x * 256 + threadIdx.x;   // over NHP*NOUTP = 16384
  int h = i >> 4, o = i & 15;
  float v = (h < NH && o < NOUT) ? W2[o * NH + h] : 0.0f;
  w2t[i] = v;
}

// ---------------- K1: cur1 = x @ W1^T + b1 (fp32 tiled GEMM) -----------------
__global__ __launch_bounds__(256) void k_gemm1(const float* __restrict__ A,
                                               const float* __restrict__ Bw,
                                               const float* __restrict__ bias,
                                               float* __restrict__ C) {
  __shared__ float As[16][68];
  __shared__ float Bs[16][68];
  const int tid = threadIdx.x;
  const int m0 = blockIdx.x << 6;
  const int n0 = blockIdx.y << 6;
  const int lr = tid >> 2;          // 0..63 row within tile
  const int lk = (tid & 3) << 2;    // k offset 0,4,8,12
  const float* aptr = A + (long)(m0 + lr) * NIN + lk;
  int nrow = n0 + lr; if (nrow > NH - 1) nrow = NH - 1;   // clamp (values unused)
  const float* bptr = Bw + (long)nrow * NIN + lk;
  const int ty = tid >> 4;          // 0..15 (m micro)
  const int tx = tid & 15;          // 0..15 (n micro)
  float acc[4][4] = {};
  float4 av = *(const float4*)aptr;
  float4 bv = *(const float4*)bptr;
  for (int kt = 16; kt <= NIN; kt += 16) {
    __syncthreads();
    As[lk + 0][lr] = av.x; As[lk + 1][lr] = av.y;
    As[lk + 2][lr] = av.z; As[lk + 3][lr] = av.w;
    Bs[lk + 0][lr] = bv.x; Bs[lk + 1][lr] = bv.y;
    Bs[lk + 2][lr] = bv.z; Bs[lk + 3][lr] = bv.w;
    __syncthreads();
    if (kt < NIN) {   // prefetch next K-tile before compute
      av = *(const float4*)(aptr + kt);
      bv = *(const float4*)(bptr + kt);
    }
#pragma unroll
    for (int kk = 0; kk < 16; ++kk) {
      float4 a4 = *(const float4*)&As[kk][ty << 2];
      float4 b4 = *(const float4*)&Bs[kk][tx << 2];
#pragma unroll
      for (int i = 0; i < 4; ++i) {
        float am = (i == 0) ? a4.x : (i == 1) ? a4.y : (i == 2) ? a4.z : a4.w;
        acc[i][0] = fmaf(am, b4.x, acc[i][0]);
        acc[i][1] = fmaf(am, b4.y, acc[i][1]);
        acc[i][2] = fmaf(am, b4.z, acc[i][2]);
        acc[i][3] = fmaf(am, b4.w, acc[i][3]);
      }
    }
  }
  const int n = n0 + (tx << 2);
  if (n < NH) {
    float4 b4 = *(const float4*)(bias + n);
#pragma unroll
    for (int i = 0; i < 4; ++i) {
      long r = m0 + (ty << 2) + i;
      float4 o4;
      o4.x = acc[i][0] + b4.x; o4.y = acc[i][1] + b4.y;
      o4.z = acc[i][2] + b4.z; o4.w = acc[i][3] + b4.w;
      *(float4*)(C + r * NH + n) = o4;
    }
  }
}

// ---------------- K2: LIF1 scan, state in regs, packed spike emission --------
// block = one batch row; thread owns 4 neurons h = j*256 + tid (j=0..3),
// packed as two float2 states (v_pk_fma). Ballot masks are wave-uniform, so
// lane L *selects* (branchless cndmask, no cross-lane op) piece L&7 at step
// L>>3, accumulating a full 64-dword 8-step tile in one register; one
// coalesced dword store per lane per 8 steps (double-buffered).
__global__ __launch_bounds__(256) void k_lif1(const float* __restrict__ cur1,
                                              uint32_t* __restrict__ spikes) {
  const int b = blockIdx.x;
  const int tid = threadIdx.x;
  const int lane = tid & 63;
  const int w = tid >> 6;
  const float* cr = cur1 + (long)b * NH;
  v2f c0, c1, syn0 = {0.f, 0.f}, syn1 = {0.f, 0.f};
  v2f mem0 = {0.f, 0.f}, mem1 = {0.f, 0.f};
  c0.x = cr[tid];
  c0.y = cr[256 + tid];
  c1.x = cr[512 + tid];
  c1.y = (768 + tid < NH) ? cr[768 + tid] : 0.0f;
  bool p0 = false, p1 = false, p2 = false, p3 = false;

  bool steq[8], lneq[8];
#pragma unroll
  for (int k = 0; k < 8; ++k) {
    steq[k] = (lane >> 3) == k;   // this lane captures at sub-step k
    lneq[k] = (lane & 7) == k;    // this lane holds mask-piece k
  }

  // per-lane store slot: t = g*8 + (lane>>3), dword k = (lane&7) of w's chunk
  uint32_t* sp = spikes + (((long)(lane >> 3) * NB + b) << 5) + (w << 3) + (lane & 7);
  const long sstep = (long)8 * NB * 32;   // dwords per 8-step group

#define STEP(TT, BUF)                                                         \
  {                                                                           \
    syn0 = 0.9f * syn0 + c0;                                                  \
    syn1 = 0.9f * syn1 + c1;                                                  \
    v2f rn0, rn1;                                                             \
    rn0.x = p0 ? -1.0f : 0.0f;  rn0.y = p1 ? -1.0f : 0.0f;                    \
    rn1.x = p2 ? -1.0f : 0.0f;  rn1.y = p3 ? -1.0f : 0.0f;                    \
    mem0 = 0.85f * mem0 + syn0 + rn0;                                         \
    mem1 = 0.85f * mem1 + syn1 + rn1;                                         \
    p0 = mem0.x > 1.0f; p1 = mem0.y > 1.0f;                                   \
    p2 = mem1.x > 1.0f; p3 = mem1.y > 1.0f;                                   \
    unsigned long long m0 = __ballot(p0), m1 = __ballot(p1);                  \
    unsigned long long m2 = __ballot(p2), m3 = __ballot(p3);                  \
    const uint32_t pc[8] = {(uint32_t)m0, (uint32_t)(m0 >> 32),               \
                            (uint32_t)m1, (uint32_t)(m1 >> 32),               \
                            (uint32_t)m2, (uint32_t)(m2 >> 32),               \
                            (uint32_t)m3, (uint32_t)(m3 >> 32)};              \
    _Pragma("unroll")                                                         \
    for (int k = 0; k < 8; ++k)                                               \
      BUF = (steq[TT] && lneq[k]) ? pc[k] : BUF;                              \
  }

  uint32_t bufA = 0, bufB = 0;
  for (int g = 0; g < 6; ++g) {      // 6 x 16 steps = 96
    STEP(0, bufA) STEP(1, bufA) STEP(2, bufA) STEP(3, bufA)
    STEP(4, bufA) STEP(5, bufA) STEP(6, bufA) STEP(7, bufA)
    *sp = bufA;  sp += sstep;
    STEP(0, bufB) STEP(1, bufB) STEP(2, bufB) STEP(3, bufB)
    STEP(4, bufB) STEP(5, bufB) STEP(6, bufB) STEP(7, bufB)
    *sp = bufB;  sp += sstep;
  }
  // tail: t = 96..99 -> lanes 0..31 of bufA
  STEP(0, bufA) STEP(1, bufA) STEP(2, bufA) STEP(3, bufA)
  if (lane < 32) *sp = bufA;
#undef STEP
}

// ---------------- K3: cur2[t][b][o] = b2[o] + sum_h bit*W2[o][h] -------------
// block = 64 rows (one t, 64 consecutive b) x 4 h-slices (one per wave).
// wave wu reads row dwords wu*8..wu*8+7; dword D (=j*2+half) covers
// h = (D>>1)*256 + wu*64 + (D&1)*32 + bit. Output pairs via v_pk_fma_f32.
__global__ __launch_bounds__(256) void k_fc2(const uint32_t* __restrict__ spikes,
                                             const float* __restrict__ w2t,
                                             const float* __restrict__ b2,
                                             float* __restrict__ cur2) {
  __shared__ float red[4][64][12];
  const int tid = threadIdx.x;
  const int lane = tid & 63;
  const int w = tid >> 6;
  const int rb = blockIdx.x;          // 12800 = NT * (NB/64)
  const int t = rb >> 7;
  const int b0 = (rb & 127) << 6;
  const uint32_t* sp = spikes + (((long)t * NB + (b0 + lane)) << 5) + (w << 3);
  const int wu = __builtin_amdgcn_readfirstlane(w);   // wave-uniform base
  const float* wbase = w2t + (wu << 10);              // wu*64*16 floats
  uint4 ma = *(const uint4*)sp;
  uint4 mb = *(const uint4*)(sp + 4);
  v2f acc2[5] = {{0,0},{0,0},{0,0},{0,0},{0,0}};
#define DO_DWORD(MVAL, D)                                                      \
  {                                                                            \
    const uint32_t m_ = (MVAL);                                                \
    _Pragma("unroll")                                                          \
    for (int jg = 0; jg < 4; ++jg) {                                           \
      const uint32_t byte_ = (m_ >> (jg << 3)) & 0xffu;                        \
      const v2f* wp = (const v2f*)(wbase +                                     \
          (((((D) >> 1) * 256) + (((D) & 1) * 32) + (jg << 3)) << 4));         \
      _Pragma("unroll")                                                        \
      for (int jj = 0; jj < 8; ++jj) {                                         \
        float bf = (float)((byte_ >> jj) & 1u);                                \
        v2f bfv = {bf, bf};                                                    \
        _Pragma("unroll")                                                      \
        for (int q = 0; q < 5; ++q)                                            \
          acc2[q] = bfv * wp[(jj << 3) + q] + acc2[q];                         \
      }                                                                        \
    }                                                                          \
  }
  DO_DWORD(ma.x, 0) DO_DWORD(ma.y, 1) DO_DWORD(ma.z, 2) DO_DWORD(ma.w, 3)
  DO_DWORD(mb.x, 4) DO_DWORD(mb.y, 5) DO_DWORD(mb.z, 6) DO_DWORD(mb.w, 7)
#undef DO_DWORD
#pragma unroll
  for (int q = 0; q < 5; ++q)
    *(v2f*)&red[w][lane][q * 2] = acc2[q];
  __syncthreads();
  const long obase = ((long)t * NB + b0) * NOUT;
  for (int i = tid; i < 640; i += 256) {
    int row = i / 10;
    int o = i - row * 10;
    float s = red[0][row][o] + red[1][row][o] + red[2][row][o] + red[3][row][o]
            + b2[o];
    cur2[obase + i] = s;
  }
}

// ---------------- K4: LIF2 scan + final outputs ------------------------------
__global__ __launch_bounds__(256) void k_lif2(float* io) {
  const int gid = blockIdx.x * 256 + threadIdx.x;   // < 81920
  float* sp = io + gid;
  float* mm = io + 8192000 + gid;
  float syn = 0.0f, mem = 0.0f;
#pragma unroll 4
  for (int t = 0; t < NT; ++t) {
    float c = sp[t * 81920];
    syn = fmaf(0.9f, syn, c);
    float r = (mem > 1.0f) ? 1.0f : 0.0f;
    mem = fmaf(0.85f, mem, syn) - r;
    sp[t * 81920] = (mem > 1.0f) ? 1.0f : 0.0f;
    mm[t * 81920] = mem;
  }
}

extern "C" void kernel_launch(void* const* d_in, const int* in_sizes, int n_in,
                              void* d_out, int out_size, void* d_ws, size_t ws_size,
                              hipStream_t stream) {
  const float* x  = (const float*)d_in[0];
  const float* W1 = (const float*)d_in[1];
  const float* b1 = (const float*)d_in[2];
  const float* W2 = (const float*)d_in[3];
  const float* b2 = (const float*)d_in[4];
  float* out = (float*)d_out;
  float* memhalf = out + 8192000;                 // cur1 staging / mem_rec
  uint32_t* spikes = (uint32_t*)d_ws;             // 104857600 B
  float* w2t = (float*)((char*)d_ws + 104857600); // 65536 B

  k_w2t<<<64, 256, 0, stream>>>(W2, w2t);
  dim3 g1(NB / 64, NHP / 64);
  k_gemm1<<<g1, 256, 0, stream>>>(x, W1, b1, memhalf);
  k_lif1<<<NB, 256, 0, stream>>>(memhalf, spikes);
  k_fc2<<<NT * (NB / 64), 256, 0, stream>>>(spikes, w2t, b2, out);
  k_lif2<<<81920 / 256, 256, 0, stream>>>(out);
}

// Round 4
// 488.409 us; speedup vs baseline: 1.5293x; 1.1720x over previous
//
#include <hip/hip_runtime.h>
#include <stdint.h>

// Problem constants
#define NB    8192
#define NIN   784
#define NH    1000
#define NHP   1024      // padded hidden
#define NOUT  10
#define NT    100

// d_out layout: [0 .. 8192000)  = spk_rec  (staging: cur2)
//               [8192000 .. )   = mem_rec  (staging: cur1)
// d_ws  layout: [0 .. 104857600)          = packed spikes [NT][NB][32] dwords
//               [104857600 .. +32768)     = W2 as bf16 [16][1024] (o-major)
//
// packed-spike row layout: 32 dwords per (t,b) row, H-LINEAR:
//   dword d, bit l  <->  h = d*32 + l

typedef float v2f __attribute__((ext_vector_type(2)));
typedef short bf16x8 __attribute__((ext_vector_type(8)));
typedef float f32x4 __attribute__((ext_vector_type(4)));

// ---------------- K0: W2 -> bf16 [16][1024], zero-padded ---------------------
__global__ __launch_bounds__(256) void k_w2t(const float* __restrict__ W2,
                                             uint16_t* __restrict__ w2bf) {
  int i = blockIdx.x * 256 + threadIdx.x;   // over 16*1024 = 16384
  int o = i >> 10, h = i & 1023;
  float v = (o < NOUT && h < NH) ? W2[o * NH + h] : 0.0f;
  uint32_t xb = __float_as_uint(v);
  uint32_t r = (xb + 0x7FFFu + ((xb >> 16) & 1u)) >> 16;   // RNE f32->bf16
  w2bf[i] = (uint16_t)r;
}

// ---------------- K1: cur1 = x @ W1^T + b1 (fp32 tiled GEMM) -----------------
__global__ __launch_bounds__(256) void k_gemm1(const float* __restrict__ A,
                                               const float* __restrict__ Bw,
                                               const float* __restrict__ bias,
                                               float* __restrict__ C) {
  __shared__ float As[16][68];
  __shared__ float Bs[16][68];
  const int tid = threadIdx.x;
  const int m0 = blockIdx.x << 6;
  const int n0 = blockIdx.y << 6;
  const int lr = tid >> 2;          // 0..63 row within tile
  const int lk = (tid & 3) << 2;    // k offset 0,4,8,12
  const float* aptr = A + (long)(m0 + lr) * NIN + lk;
  int nrow = n0 + lr; if (nrow > NH - 1) nrow = NH - 1;   // clamp (values unused)
  const float* bptr = Bw + (long)nrow * NIN + lk;
  const int ty = tid >> 4;          // 0..15 (m micro)
  const int tx = tid & 15;          // 0..15 (n micro)
  float acc[4][4] = {};
  float4 av = *(const float4*)aptr;
  float4 bv = *(const float4*)bptr;
  for (int kt = 16; kt <= NIN; kt += 16) {
    __syncthreads();
    As[lk + 0][lr] = av.x; As[lk + 1][lr] = av.y;
    As[lk + 2][lr] = av.z; As[lk + 3][lr] = av.w;
    Bs[lk + 0][lr] = bv.x; Bs[lk + 1][lr] = bv.y;
    Bs[lk + 2][lr] = bv.z; Bs[lk + 3][lr] = bv.w;
    __syncthreads();
    if (kt < NIN) {   // prefetch next K-tile before compute
      av = *(const float4*)(aptr + kt);
      bv = *(const float4*)(bptr + kt);
    }
#pragma unroll
    for (int kk = 0; kk < 16; ++kk) {
      float4 a4 = *(const float4*)&As[kk][ty << 2];
      float4 b4 = *(const float4*)&Bs[kk][tx << 2];
#pragma unroll
      for (int i = 0; i < 4; ++i) {
        float am = (i == 0) ? a4.x : (i == 1) ? a4.y : (i == 2) ? a4.z : a4.w;
        acc[i][0] = fmaf(am, b4.x, acc[i][0]);
        acc[i][1] = fmaf(am, b4.y, acc[i][1]);
        acc[i][2] = fmaf(am, b4.z, acc[i][2]);
        acc[i][3] = fmaf(am, b4.w, acc[i][3]);
      }
    }
  }
  const int n = n0 + (tx << 2);
  if (n < NH) {
    float4 b4 = *(const float4*)(bias + n);
#pragma unroll
    for (int i = 0; i < 4; ++i) {
      long r = m0 + (ty << 2) + i;
      float4 o4;
      o4.x = acc[i][0] + b4.x; o4.y = acc[i][1] + b4.y;
      o4.z = acc[i][2] + b4.z; o4.w = acc[i][3] + b4.w;
      *(float4*)(C + r * NH + n) = o4;
    }
  }
}

// ---------------- K2: LIF1 scan, h-linear packed spike emission --------------
// Thread (w, lane) owns neurons h = w*256 + j*64 + lane (j=0..3), so wave w's
// ballot for j covers h-dwords w*8 + j*2 + {0,1}: the wave's 8 pieces are the
// CONTIGUOUS h-linear dwords [w*8, w*8+8) of the row. Lane L captures piece
// L&7 at sub-step L>>3 via branchless cndmask; one coalesced dword store per
// lane per 8 steps (double-buffered).
__global__ __launch_bounds__(256) void k_lif1(const float* __restrict__ cur1,
                                              uint32_t* __restrict__ spikes) {
  const int b = blockIdx.x;
  const int tid = threadIdx.x;
  const int lane = tid & 63;
  const int w = tid >> 6;
  const float* cr = cur1 + (long)b * NH + w * 256 + lane;
  v2f c0, c1, syn0 = {0.f, 0.f}, syn1 = {0.f, 0.f};
  v2f mem0 = {0.f, 0.f}, mem1 = {0.f, 0.f};
  c0.x = cr[0];
  c0.y = cr[64];
  c1.x = cr[128];
  c1.y = (w * 256 + 192 + lane < NH) ? cr[192] : 0.0f;
  bool p0 = false, p1 = false, p2 = false, p3 = false;

  bool steq[8], lneq[8];
#pragma unroll
  for (int k = 0; k < 8; ++k) {
    steq[k] = (lane >> 3) == k;   // this lane captures at sub-step k
    lneq[k] = (lane & 7) == k;    // this lane holds mask-piece k
  }

  // per-lane store slot: t = g*8 + (lane>>3), dword d = w*8 + (lane&7)
  uint32_t* sp = spikes + (((long)(lane >> 3) * NB + b) << 5) + (w << 3) + (lane & 7);
  const long sstep = (long)8 * NB * 32;   // dwords per 8-step group

#define STEP(TT, BUF)                                                         \
  {                                                                           \
    syn0 = 0.9f * syn0 + c0;                                                  \
    syn1 = 0.9f * syn1 + c1;                                                  \
    v2f rn0, rn1;                                                             \
    rn0.x = p0 ? -1.0f : 0.0f;  rn0.y = p1 ? -1.0f : 0.0f;                    \
    rn1.x = p2 ? -1.0f : 0.0f;  rn1.y = p3 ? -1.0f : 0.0f;                    \
    mem0 = 0.85f * mem0 + syn0 + rn0;                                         \
    mem1 = 0.85f * mem1 + syn1 + rn1;                                         \
    p0 = mem0.x > 1.0f; p1 = mem0.y > 1.0f;                                   \
    p2 = mem1.x > 1.0f; p3 = mem1.y > 1.0f;                                   \
    unsigned long long m0 = __ballot(p0), m1 = __ballot(p1);                  \
    unsigned long long m2 = __ballot(p2), m3 = __ballot(p3);                  \
    const uint32_t pc[8] = {(uint32_t)m0, (uint32_t)(m0 >> 32),               \
                            (uint32_t)m1, (uint32_t)(m1 >> 32),               \
                            (uint32_t)m2, (uint32_t)(m2 >> 32),               \
                            (uint32_t)m3, (uint32_t)(m3 >> 32)};              \
    _Pragma("unroll")                                                         \
    for (int k = 0; k < 8; ++k)                                               \
      BUF = (steq[TT] && lneq[k]) ? pc[k] : BUF;                              \
  }

  uint32_t bufA = 0, bufB = 0;
  for (int g = 0; g < 6; ++g) {      // 6 x 16 steps = 96
    STEP(0, bufA) STEP(1, bufA) STEP(2, bufA) STEP(3, bufA)
    STEP(4, bufA) STEP(5, bufA) STEP(6, bufA) STEP(7, bufA)
    *sp = bufA;  sp += sstep;
    STEP(0, bufB) STEP(1, bufB) STEP(2, bufB) STEP(3, bufB)
    STEP(4, bufB) STEP(5, bufB) STEP(6, bufB) STEP(7, bufB)
    *sp = bufB;  sp += sstep;
  }
  // tail: t = 96..99 -> lanes 0..31 of bufA
  STEP(0, bufA) STEP(1, bufA) STEP(2, bufA) STEP(3, bufA)
  if (lane < 32) *sp = bufA;
#undef STEP
}

// ---------------- K3: cur2 = spikes @ W2^T + b2 via bf16 MFMA ----------------
// C[o][b] tile = W2bf(A, 16xK) x spikes(B, Kx16). k-slot (kc,g,j) <-> h =
// g*256 + kc*8 + j, so lane (x=l&15, g=l>>4) B-frag = byte kc of its OWN
// 32-byte mask slice (dwords [g*8,g*8+8) of row b0+x), and A-frag = 16B
// contiguous from w2bf[x][g*256+kc*8]. Bit->bf16 pair: (b1*0xFFFE+t)*0x3F80.
// Wave = 2 tiles (32 rows); no LDS, no syncthreads.
__global__ __launch_bounds__(256) void k_fc2(const uint32_t* __restrict__ spikes,
                                             const uint16_t* __restrict__ w2bf,
                                             const float* __restrict__ b2,
                                             float* __restrict__ cur2) {
  const int tid = threadIdx.x;
  const int lane = tid & 63;
  const int w = tid >> 6;
  const int wid = blockIdx.x * 4 + w;      // 0..25599, 32 rows each
  const int t = wid >> 8;                  // 256 wids per t (8192/32)
  const int bb = (wid & 255) * 32;
  const int x = lane & 15, g = lane >> 4;

  uint32_t m[2][8];
  const uint32_t* base = spikes + (((long)t * NB + bb + x) << 5) + (g << 3);
#pragma unroll
  for (int i = 0; i < 2; ++i) {
    const uint32_t* p = base + i * 16 * 32;
    *(uint4*)&m[i][0] = *(const uint4*)p;
    *(uint4*)&m[i][4] = *(const uint4*)(p + 4);
  }
  const uint16_t* wbase = w2bf + (x << 10) + (g << 8);
  f32x4 acc[2] = {{0,0,0,0},{0,0,0,0}};
#pragma unroll
  for (int kc = 0; kc < 32; ++kc) {
    bf16x8 afrag = *(const bf16x8*)(wbase + (kc << 3));
#pragma unroll
    for (int i = 0; i < 2; ++i) {
      const uint32_t xm = m[i][kc >> 2];
      const int sh = (kc & 3) << 3;
      union { uint32_t u[4]; bf16x8 v; } bf;
#pragma unroll
      for (int j = 0; j < 4; ++j) {
        uint32_t t2 = (xm >> (sh + 2 * j)) & 3u;
        uint32_t hi = (xm >> (sh + 2 * j + 1)) & 1u;
        bf.u[j] = (hi * 0xFFFEu + t2) * 0x3F80u;
      }
      acc[i] = __builtin_amdgcn_mfma_f32_16x16x32_bf16(afrag, bf.v, acc[i],
                                                       0, 0, 0);
    }
  }
  // C/D: col(N=b) = lane&15, row(M=o) = g*4 + r
  float bias[4];
#pragma unroll
  for (int r = 0; r < 4; ++r) {
    int o = (g << 2) + r;
    bias[r] = (o < NOUT) ? b2[o] : 0.0f;
  }
#pragma unroll
  for (int i = 0; i < 2; ++i) {
    long rowg = (long)t * NB + bb + i * 16 + x;
#pragma unroll
    for (int r = 0; r < 4; ++r) {
      int o = (g << 2) + r;
      if (o < NOUT) cur2[rowg * NOUT + o] = acc[i][r] + bias[r];
    }
  }
}

// ---------------- K4: LIF2 scan + final outputs ------------------------------
__global__ __launch_bounds__(256) void k_lif2(float* io) {
  const int gid = blockIdx.x * 256 + threadIdx.x;   // < 81920
  float* sp = io + gid;
  float* mm = io + 8192000 + gid;
  float syn = 0.0f, mem = 0.0f;
#pragma unroll 4
  for (int t = 0; t < NT; ++t) {
    float c = sp[t * 81920];
    syn = fmaf(0.9f, syn, c);
    float r = (mem > 1.0f) ? 1.0f : 0.0f;
    mem = fmaf(0.85f, mem, syn) - r;
    sp[t * 81920] = (mem > 1.0f) ? 1.0f : 0.0f;
    mm[t * 81920] = mem;
  }
}

extern "C" void kernel_launch(void* const* d_in, const int* in_sizes, int n_in,
                              void* d_out, int out_size, void* d_ws, size_t ws_size,
                              hipStream_t stream) {
  const float* x  = (const float*)d_in[0];
  const float* W1 = (const float*)d_in[1];
  const float* b1 = (const float*)d_in[2];
  const float* W2 = (const float*)d_in[3];
  const float* b2 = (const float*)d_in[4];
  float* out = (float*)d_out;
  float* memhalf = out + 8192000;                   // cur1 staging / mem_rec
  uint32_t* spikes = (uint32_t*)d_ws;               // 104857600 B
  uint16_t* w2bf = (uint16_t*)((char*)d_ws + 104857600);  // 32768 B

  k_w2t<<<64, 256, 0, stream>>>(W2, w2bf);
  dim3 g1(NB / 64, NHP / 64);
  k_gemm1<<<g1, 256, 0, stream>>>(x, W1, b1, memhalf);
  k_lif1<<<NB, 256, 0, stream>>>(memhalf, spikes);
  k_fc2<<<25600 / 4, 256, 0, stream>>>(spikes, w2bf, b2, out);
  k_lif2<<<81920 / 256, 256, 0, stream>>>(out);
}

// Round 5
// 348.031 us; speedup vs baseline: 2.1461x; 1.4033x over previous
//
#include <hip/hip_runtime.h>
#include <stdint.h>

#define NB   8192
#define NIN  784
#define KP   800       // K padded to 25*32 for gemm1 MFMA
#define NH   1000
#define NHP  1024
#define NOUT 10
#define NT   100

typedef float v2f    __attribute__((ext_vector_type(2)));
typedef short bf16x8 __attribute__((ext_vector_type(8)));
typedef float f32x4  __attribute__((ext_vector_type(4)));

// ---------------------------------------------------------------------------
// d_ws: [0, 100663296)            spk32 [12][NB][256] u32  (groups g: t=8g..8g+7)
//       [100663296, 104857600)    spk16 [NB][256] u16      (t=96..99, nibbles 0..3)
//       [104857600, +32768)       w2bf  [16][1024] bf16
// d_out spk half [0, 8192000 floats): staging xh[8192][800]bf16 @0B,
//       xl @13107200B, wh[1024][800] @26214400B, wl @27852800B  (cur2 later)
// d_out mem half: cur1 [8192][1000] f32 (mem_rec later)
// spike dword [g][b][q]: nibble n bit j = spike(t=8g+n, h=4q+j)
// ---------------------------------------------------------------------------

__device__ __forceinline__ uint16_t f2bf(float v) {
  uint32_t x = __float_as_uint(v);
  return (uint16_t)((x + 0x7FFFu + ((x >> 16) & 1u)) >> 16);
}

// ---------------- K0: W2 -> bf16 [16][1024] --------------------------------
__global__ __launch_bounds__(256) void k_w2bf(const float* __restrict__ W2,
                                              uint16_t* __restrict__ w2bf) {
  int i = blockIdx.x * 256 + threadIdx.x;   // 16*1024
  int o = i >> 10, h = i & 1023;
  float v = (o < NOUT && h < NH) ? W2[o * NH + h] : 0.0f;
  w2bf[i] = f2bf(v);
}

// ---------------- K0b: split fp32 -> (bf16 hi, bf16 lo), zero-padded -------
__global__ __launch_bounds__(256) void k_split(const float* __restrict__ src,
                                               uint16_t* __restrict__ hi,
                                               uint16_t* __restrict__ lo,
                                               int rows_valid, int total) {
  int i = blockIdx.x * 256 + threadIdx.x;
  if (i >= total) return;
  int r = i / KP, k = i - r * KP;
  float v = (r < rows_valid && k < NIN) ? src[r * NIN + k] : 0.0f;
  uint16_t h = f2bf(v);
  float hv = __uint_as_float(((uint32_t)h) << 16);
  hi[i] = h;
  lo[i] = f2bf(v - hv);
}

// ---------------- K1: cur1 = x @ W1^T + b1, split-bf16 MFMA ----------------
// A = x rows (m), B = W1 rows (n); per wave 64m x 64n (4x4 tiles), 3-term
// split products. Free k-bijection: both frags use (g,j) -> k = g*8+j.
// C/D: row(m) = g*4+r, col(n) = x (proven mapping from fc2 R4).
__global__ __launch_bounds__(256) void k_gemm1m(
    const uint16_t* __restrict__ xh, const uint16_t* __restrict__ xl,
    const uint16_t* __restrict__ wh, const uint16_t* __restrict__ wl,
    const float* __restrict__ b1, float* __restrict__ C) {
  const int lane = threadIdx.x & 63, w = threadIdx.x >> 6;
  const int x = lane & 15, g = lane >> 4;
  const int m0 = blockIdx.x << 6;
  const int n0 = (blockIdx.y << 8) + (w << 6);
  long ar[4], br[4];
#pragma unroll
  for (int s = 0; s < 4; ++s) {
    ar[s] = (long)(m0 + s * 16 + x) * KP + (g << 3);
    br[s] = (long)(n0 + s * 16 + x) * KP + (g << 3);
  }
  f32x4 acc[4][4];
#pragma unroll
  for (int mt = 0; mt < 4; ++mt)
#pragma unroll
    for (int nt = 0; nt < 4; ++nt) acc[mt][nt] = (f32x4){0, 0, 0, 0};

  for (int kc = 0; kc < 25; ++kc) {
    const int ko = kc << 5;
    bf16x8 afh[4], afl[4], bfh[4], bfl[4];
#pragma unroll
    for (int s = 0; s < 4; ++s) {
      afh[s] = *(const bf16x8*)(xh + ar[s] + ko);
      afl[s] = *(const bf16x8*)(xl + ar[s] + ko);
      bfh[s] = *(const bf16x8*)(wh + br[s] + ko);
      bfl[s] = *(const bf16x8*)(wl + br[s] + ko);
    }
#pragma unroll
    for (int mt = 0; mt < 4; ++mt)
#pragma unroll
      for (int nt = 0; nt < 4; ++nt) {
        acc[mt][nt] = __builtin_amdgcn_mfma_f32_16x16x32_bf16(
            afh[mt], bfh[nt], acc[mt][nt], 0, 0, 0);
        acc[mt][nt] = __builtin_amdgcn_mfma_f32_16x16x32_bf16(
            afh[mt], bfl[nt], acc[mt][nt], 0, 0, 0);
        acc[mt][nt] = __builtin_amdgcn_mfma_f32_16x16x32_bf16(
            afl[mt], bfh[nt], acc[mt][nt], 0, 0, 0);
      }
  }
#pragma unroll
  for (int nt = 0; nt < 4; ++nt) {
    int n = n0 + (nt << 4) + x;
    if (n < NH) {
      float bias = b1[n];
#pragma unroll
      for (int mt = 0; mt < 4; ++mt)
#pragma unroll
        for (int r = 0; r < 4; ++r) {
          int m = m0 + (mt << 4) + (g << 2) + r;
          C[(long)m * NH + n] = acc[mt][nt][r] + bias;
        }
    }
  }
}

// ---------------- K2: LIF1 scan, lane-local nibble packing -----------------
// thread q owns h = 4q..4q+3; 4 spike bits stay in-register (no ballot),
// 8 steps accumulate one dword, stored coalesced once per group.
__global__ __launch_bounds__(256) void k_lif1(const float* __restrict__ cur1,
                                              uint32_t* __restrict__ spk32,
                                              uint16_t* __restrict__ spk16) {
  const int b = blockIdx.x, q = threadIdx.x;
  float4 c4 = {0, 0, 0, 0};
  if (q < 250) c4 = *(const float4*)(cur1 + (long)b * NH + (q << 2));
  v2f ca = {c4.x, c4.y}, cb = {c4.z, c4.w};
  v2f syna = {0, 0}, synb = {0, 0}, mema = {0, 0}, memb = {0, 0};
  bool p0 = false, p1 = false, p2 = false, p3 = false;
  uint32_t* sp = spk32 + ((long)b << 8) + q;
  const long gstep = (long)NB << 8;
  uint32_t buf;
#define STEP(N)                                                   \
  {                                                               \
    syna = 0.9f * syna + ca;  synb = 0.9f * synb + cb;            \
    v2f ra = {p0 ? -1.0f : 0.0f, p1 ? -1.0f : 0.0f};              \
    v2f rb = {p2 ? -1.0f : 0.0f, p3 ? -1.0f : 0.0f};              \
    mema = 0.85f * mema + syna + ra;                              \
    memb = 0.85f * memb + synb + rb;                              \
    p0 = mema.x > 1.0f; p1 = mema.y > 1.0f;                       \
    p2 = memb.x > 1.0f; p3 = memb.y > 1.0f;                       \
    uint32_t bb0 = p0, bb1 = p1, bb2 = p2, bb3 = p3;              \
    buf |= ((bb0 | (bb1 << 1) | (bb2 << 2) | (bb3 << 3)) << (4 * (N))); \
  }
  for (int gi = 0; gi < 12; ++gi) {
    buf = 0;
    STEP(0) STEP(1) STEP(2) STEP(3) STEP(4) STEP(5) STEP(6) STEP(7)
    *sp = buf;  sp += gstep;
  }
  buf = 0;
  STEP(0) STEP(1) STEP(2) STEP(3)
  spk16[((long)b << 8) + q] = (uint16_t)buf;
#undef STEP
}

// ---------------- K3a: fc2 for groups 0..11 (8 t per wave) -----------------
// wave: (group gq, 32 rows). lane (x,g): B bits for h = g*256+8kc+j from
// dwords [gq][row][g*64+2kc +{0,1}] nibble t; A = w2bf[x][g*256+8kc..+8).
__global__ __launch_bounds__(256) void k_fc2a(const uint32_t* __restrict__ spk,
                                              const uint16_t* __restrict__ w2bf,
                                              const float* __restrict__ b2,
                                              float* __restrict__ cur2) {
  const int lane = threadIdx.x & 63, w = threadIdx.x >> 6;
  const int x = lane & 15, g = lane >> 4;
  const int wid = blockIdx.x * 4 + w;       // 0..3071
  const int gq = wid >> 8;                  // group 0..11
  const int bb = (wid & 255) << 5;          // 32 rows
  const uint16_t* wb = w2bf + (x << 10) + (g << 8);
  const uint32_t* s0 = spk + (((long)gq * NB + bb + x) << 8) + (g << 6);
  const uint32_t* s1 = s0 + (16 << 8);
  f32x4 acc[2][8];
#pragma unroll
  for (int i = 0; i < 2; ++i)
#pragma unroll
    for (int t = 0; t < 8; ++t) acc[i][t] = (f32x4){0, 0, 0, 0};

#pragma unroll 2
  for (int kc = 0; kc < 32; ++kc) {
    bf16x8 af = *(const bf16x8*)(wb + (kc << 3));
    uint2 d0 = *(const uint2*)(s0 + (kc << 1));
    uint2 d1 = *(const uint2*)(s1 + (kc << 1));
#pragma unroll
    for (int i = 0; i < 2; ++i) {
      uint2 d = i ? d1 : d0;
#pragma unroll
      for (int t = 0; t < 8; ++t) {
        uint32_t byte_ = ((d.x >> (4 * t)) & 0xFu) |
                         (((d.y >> (4 * t)) & 0xFu) << 4);
        union { uint32_t u[4]; bf16x8 v; } bf;
#pragma unroll
        for (int j = 0; j < 4; ++j) {
          uint32_t t2 = (byte_ >> (2 * j)) & 3u;
          uint32_t hb = (byte_ >> (2 * j + 1)) & 1u;
          bf.u[j] = (hb * 0xFFFEu + t2) * 0x3F80u;
        }
        acc[i][t] = __builtin_amdgcn_mfma_f32_16x16x32_bf16(af, bf.v,
                                                            acc[i][t], 0, 0, 0);
      }
    }
  }
  float bias[4];
#pragma unroll
  for (int r = 0; r < 4; ++r) {
    int o = (g << 2) + r;
    bias[r] = (o < NOUT) ? b2[o] : 0.0f;
  }
#pragma unroll
  for (int i = 0; i < 2; ++i) {
    long row = bb + (i << 4) + x;
#pragma unroll
    for (int t = 0; t < 8; ++t) {
      long tb = ((long)(gq * 8 + t) * NB + row) * NOUT;
#pragma unroll
      for (int r = 0; r < 4; ++r) {
        int o = (g << 2) + r;
        if (o < NOUT) cur2[tb + o] = acc[i][t][r] + bias[r];
      }
    }
  }
}

// ---------------- K3b: fc2 for t=96..99 (u16 tail layout) ------------------
__global__ __launch_bounds__(256) void k_fc2b(const uint32_t* __restrict__ spk16d,
                                              const uint16_t* __restrict__ w2bf,
                                              const float* __restrict__ b2,
                                              float* __restrict__ cur2) {
  const int lane = threadIdx.x & 63, w = threadIdx.x >> 6;
  const int x = lane & 15, g = lane >> 4;
  const int wid = blockIdx.x * 4 + w;       // 0..255
  const int bb = wid << 5;
  const uint16_t* wb = w2bf + (x << 10) + (g << 8);
  // dword index for (row, quad Q=g*64+2kc): (row<<7) + (g<<5) + kc
  const uint32_t* s0 = spk16d + ((long)(bb + x) << 7) + (g << 5);
  const uint32_t* s1 = s0 + (16 << 7);
  f32x4 acc[2][4];
#pragma unroll
  for (int i = 0; i < 2; ++i)
#pragma unroll
    for (int t = 0; t < 4; ++t) acc[i][t] = (f32x4){0, 0, 0, 0};

#pragma unroll 2
  for (int kc = 0; kc < 32; ++kc) {
    bf16x8 af = *(const bf16x8*)(wb + (kc << 3));
    uint32_t d0 = s0[kc];
    uint32_t d1 = s1[kc];
#pragma unroll
    for (int i = 0; i < 2; ++i) {
      uint32_t d = i ? d1 : d0;
#pragma unroll
      for (int t = 0; t < 4; ++t) {
        uint32_t byte_ = ((d >> (4 * t)) & 0xFu) |
                         (((d >> (16 + 4 * t)) & 0xFu) << 4);
        union { uint32_t u[4]; bf16x8 v; } bf;
#pragma unroll
        for (int j = 0; j < 4; ++j) {
          uint32_t t2 = (byte_ >> (2 * j)) & 3u;
          uint32_t hb = (byte_ >> (2 * j + 1)) & 1u;
          bf.u[j] = (hb * 0xFFFEu + t2) * 0x3F80u;
        }
        acc[i][t] = __builtin_amdgcn_mfma_f32_16x16x32_bf16(af, bf.v,
                                                            acc[i][t], 0, 0, 0);
      }
    }
  }
  float bias[4];
#pragma unroll
  for (int r = 0; r < 4; ++r) {
    int o = (g << 2) + r;
    bias[r] = (o < NOUT) ? b2[o] : 0.0f;
  }
#pragma unroll
  for (int i = 0; i < 2; ++i) {
    long row = bb + (i << 4) + x;
#pragma unroll
    for (int t = 0; t < 4; ++t) {
      long tb = ((long)(96 + t) * NB + row) * NOUT;
#pragma unroll
      for (int r = 0; r < 4; ++r) {
        int o = (g << 2) + r;
        if (o < NOUT) cur2[tb + o] = acc[i][t][r] + bias[r];
      }
    }
  }
}

// ---------------- K4: LIF2 scan, 4-deep prefetch ---------------------------
__global__ __launch_bounds__(256) void k_lif2(float* io) {
  const int gid = blockIdx.x * 256 + threadIdx.x;   // < 81920
  float* sp = io + gid;
  float* mm = io + 8192000 + gid;
  float syn = 0.0f, mem = 0.0f;
  float c0 = sp[0], c1 = sp[81920], c2 = sp[2 * 81920], c3 = sp[3 * 81920];
  for (int t = 0; t < NT; t += 4) {
    // prefetch next 4 (reads past t=99 land in mem-half garbage, discarded)
    float n0 = sp[(t + 4) * 81920], n1 = sp[(t + 5) * 81920];
    float n2 = sp[(t + 6) * 81920], n3 = sp[(t + 7) * 81920];
#define L2STEP(TT, CC)                                   \
    {                                                    \
      syn = fmaf(0.9f, syn, CC);                         \
      float r = (mem > 1.0f) ? 1.0f : 0.0f;              \
      mem = fmaf(0.85f, mem, syn) - r;                   \
      sp[(t + TT) * 81920] = (mem > 1.0f) ? 1.0f : 0.0f; \
      mm[(t + TT) * 81920] = mem;                        \
    }
    L2STEP(0, c0) L2STEP(1, c1) L2STEP(2, c2) L2STEP(3, c3)
#undef L2STEP
    c0 = n0; c1 = n1; c2 = n2; c3 = n3;
  }
}

extern "C" void kernel_launch(void* const* d_in, const int* in_sizes, int n_in,
                              void* d_out, int out_size, void* d_ws, size_t ws_size,
                              hipStream_t stream) {
  const float* x  = (const float*)d_in[0];
  const float* W1 = (const float*)d_in[1];
  const float* b1 = (const float*)d_in[2];
  const float* W2 = (const float*)d_in[3];
  const float* b2 = (const float*)d_in[4];
  float* out = (float*)d_out;
  float* memhalf = out + 8192000;                          // cur1 / mem_rec

  uint32_t* spk32 = (uint32_t*)d_ws;                       // 100663296 B
  uint32_t* spk16d = (uint32_t*)((char*)d_ws + 100663296); // 4194304 B
  uint16_t* spk16 = (uint16_t*)spk16d;
  uint16_t* w2bf = (uint16_t*)((char*)d_ws + 104857600);   // 32768 B

  uint16_t* xh = (uint16_t*)d_out;                         // staging in spk half
  uint16_t* xl = (uint16_t*)((char*)d_out + 13107200);
  uint16_t* wh = (uint16_t*)((char*)d_out + 26214400);
  uint16_t* wl = (uint16_t*)((char*)d_out + 27852800);

  k_w2bf<<<64, 256, 0, stream>>>(W2, w2bf);
  k_split<<<25600, 256, 0, stream>>>(x, xh, xl, NB, NB * KP);
  k_split<<<3200, 256, 0, stream>>>(W1, wh, wl, NH, NHP * KP);
  dim3 gg(128, 4);
  k_gemm1m<<<gg, 256, 0, stream>>>(xh, xl, wh, wl, b1, memhalf);
  k_lif1<<<NB, 256, 0, stream>>>(memhalf, spk32, spk16);
  k_fc2a<<<768, 256, 0, stream>>>(spk32, w2bf, b2, out);
  k_fc2b<<<64, 256, 0, stream>>>(spk16d, w2bf, b2, out);
  k_lif2<<<320, 256, 0, stream>>>(out);
}

// Round 6
// 346.129 us; speedup vs baseline: 2.1579x; 1.0055x over previous
//
#include <hip/hip_runtime.h>
#include <stdint.h>

#define NB   8192
#define NIN  784
#define KP   800       // K padded to 25*32 for gemm1 MFMA
#define NH   1000
#define NHP  1024
#define NOUT 10
#define NT   100

typedef float v2f    __attribute__((ext_vector_type(2)));
typedef short bf16x8 __attribute__((ext_vector_type(8)));
typedef float f32x4  __attribute__((ext_vector_type(4)));

// ---------------------------------------------------------------------------
// d_ws: [0, 100663296)            spk32 [12][NB][256] u32  (groups g: t=8g..8g+7)
//       [100663296, 104857600)    spk16 [NB][256] u16      (t=96..99, nibbles 0..3)
//       [104857600, +32768)       w2bf  [16][1024] bf16
// d_out spk half [0, 8192000 floats): staging xh[8192][800]bf16 @0B,
//       xl @13107200B, wh[1024][800] @26214400B, wl @27852800B  (cur2 later)
// d_out mem half: cur1 [8192][1000] f32 (mem_rec later)
// spike dword [g][b][q]: nibble n bit j = spike(t=8g+n, h=4q+j)
// ---------------------------------------------------------------------------

__device__ __forceinline__ uint16_t f2bf(float v) {
  uint32_t x = __float_as_uint(v);
  return (uint16_t)((x + 0x7FFFu + ((x >> 16) & 1u)) >> 16);
}

// ---------------- K0: W2 -> bf16 [16][1024] --------------------------------
__global__ __launch_bounds__(256) void k_w2bf(const float* __restrict__ W2,
                                              uint16_t* __restrict__ w2bf) {
  int i = blockIdx.x * 256 + threadIdx.x;   // 16*1024
  int o = i >> 10, h = i & 1023;
  float v = (o < NOUT && h < NH) ? W2[o * NH + h] : 0.0f;
  w2bf[i] = f2bf(v);
}

// ---------------- K0b: split fp32 -> (bf16 hi, bf16 lo), zero-padded -------
__global__ __launch_bounds__(256) void k_split(const float* __restrict__ src,
                                               uint16_t* __restrict__ hi,
                                               uint16_t* __restrict__ lo,
                                               int rows_valid, int total) {
  int i = blockIdx.x * 256 + threadIdx.x;
  if (i >= total) return;
  int r = i / KP, k = i - r * KP;
  float v = (r < rows_valid && k < NIN) ? src[r * NIN + k] : 0.0f;
  uint16_t h = f2bf(v);
  float hv = __uint_as_float(((uint32_t)h) << 16);
  hi[i] = h;
  lo[i] = f2bf(v - hv);
}

// ---------------- K1: cur1 = x @ W1^T + b1, split-bf16 MFMA ----------------
__global__ __launch_bounds__(256) void k_gemm1m(
    const uint16_t* __restrict__ xh, const uint16_t* __restrict__ xl,
    const uint16_t* __restrict__ wh, const uint16_t* __restrict__ wl,
    const float* __restrict__ b1, float* __restrict__ C) {
  const int lane = threadIdx.x & 63, w = threadIdx.x >> 6;
  const int x = lane & 15, g = lane >> 4;
  const int m0 = blockIdx.x << 6;
  const int n0 = (blockIdx.y << 8) + (w << 6);
  long ar[4], br[4];
#pragma unroll
  for (int s = 0; s < 4; ++s) {
    ar[s] = (long)(m0 + s * 16 + x) * KP + (g << 3);
    br[s] = (long)(n0 + s * 16 + x) * KP + (g << 3);
  }
  f32x4 acc[4][4];
#pragma unroll
  for (int mt = 0; mt < 4; ++mt)
#pragma unroll
    for (int nt = 0; nt < 4; ++nt) acc[mt][nt] = (f32x4){0, 0, 0, 0};

  for (int kc = 0; kc < 25; ++kc) {
    const int ko = kc << 5;
    bf16x8 afh[4], afl[4], bfh[4], bfl[4];
#pragma unroll
    for (int s = 0; s < 4; ++s) {
      afh[s] = *(const bf16x8*)(xh + ar[s] + ko);
      afl[s] = *(const bf16x8*)(xl + ar[s] + ko);
      bfh[s] = *(const bf16x8*)(wh + br[s] + ko);
      bfl[s] = *(const bf16x8*)(wl + br[s] + ko);
    }
#pragma unroll
    for (int mt = 0; mt < 4; ++mt)
#pragma unroll
      for (int nt = 0; nt < 4; ++nt) {
        acc[mt][nt] = __builtin_amdgcn_mfma_f32_16x16x32_bf16(
            afh[mt], bfh[nt], acc[mt][nt], 0, 0, 0);
        acc[mt][nt] = __builtin_amdgcn_mfma_f32_16x16x32_bf16(
            afh[mt], bfl[nt], acc[mt][nt], 0, 0, 0);
        acc[mt][nt] = __builtin_amdgcn_mfma_f32_16x16x32_bf16(
            afl[mt], bfh[nt], acc[mt][nt], 0, 0, 0);
      }
  }
#pragma unroll
  for (int nt = 0; nt < 4; ++nt) {
    int n = n0 + (nt << 4) + x;
    if (n < NH) {
      float bias = b1[n];
#pragma unroll
      for (int mt = 0; mt < 4; ++mt)
#pragma unroll
        for (int r = 0; r < 4; ++r) {
          int m = m0 + (mt << 4) + (g << 2) + r;
          C[(long)m * NH + n] = acc[mt][nt][r] + bias;
        }
    }
  }
}

// ---------------- K2: LIF1 scan, forced v_pk_fma, nibble packing -----------
// thread q owns h = 4q..4q+3 (2 v2f pairs). Per step: 3 pk ops per pair via
// inline asm (compiler scalarizes float2 math otherwise), cmp doubles as
// spike bit + next-step reset predicate. One coalesced dword store / 8 steps.
__global__ __launch_bounds__(256) void k_lif1(const float* __restrict__ cur1,
                                              uint32_t* __restrict__ spk32,
                                              uint16_t* __restrict__ spk16) {
  const int b = blockIdx.x, q = threadIdx.x;
  float4 c4 = {0, 0, 0, 0};
  if (q < 250) c4 = *(const float4*)(cur1 + (long)b * NH + (q << 2));
  v2f ca = {c4.x, c4.y}, cb = {c4.z, c4.w};
  v2f syna = {0, 0}, synb = {0, 0}, mema = {0, 0}, memb = {0, 0};
  const v2f k9 = {0.9f, 0.9f}, k85 = {0.85f, 0.85f};
  bool p0 = false, p1 = false, p2 = false, p3 = false;
  uint32_t* sp = spk32 + ((long)b << 8) + q;
  const long gstep = (long)NB << 8;
  uint32_t buf;
#define STEP(N)                                                             \
  {                                                                         \
    asm("v_pk_fma_f32 %0, %1, %0, %2" : "+v"(syna) : "v"(k9), "v"(ca));     \
    asm("v_pk_fma_f32 %0, %1, %0, %2" : "+v"(synb) : "v"(k9), "v"(cb));     \
    v2f rna, rnb;                                                           \
    rna.x = p0 ? -1.0f : 0.0f;  rna.y = p1 ? -1.0f : 0.0f;                  \
    rnb.x = p2 ? -1.0f : 0.0f;  rnb.y = p3 ? -1.0f : 0.0f;                  \
    asm("v_pk_fma_f32 %0, %1, %0, %2" : "+v"(mema) : "v"(k85), "v"(syna));  \
    asm("v_pk_fma_f32 %0, %1, %0, %2" : "+v"(memb) : "v"(k85), "v"(synb));  \
    asm("v_pk_add_f32 %0, %0, %1" : "+v"(mema) : "v"(rna));                 \
    asm("v_pk_add_f32 %0, %0, %1" : "+v"(memb) : "v"(rnb));                 \
    p0 = mema.x > 1.0f; p1 = mema.y > 1.0f;                                 \
    p2 = memb.x > 1.0f; p3 = memb.y > 1.0f;                                 \
    uint32_t nib = (p0 ? 1u : 0u) | (p1 ? 2u : 0u) |                        \
                   (p2 ? 4u : 0u) | (p3 ? 8u : 0u);                         \
    buf |= nib << (4 * (N));                                                \
  }
  for (int gi = 0; gi < 12; ++gi) {
    buf = 0;
    STEP(0) STEP(1) STEP(2) STEP(3) STEP(4) STEP(5) STEP(6) STEP(7)
    *sp = buf;  sp += gstep;
  }
  buf = 0;
  STEP(0) STEP(1) STEP(2) STEP(3)
  spk16[((long)b << 8) + q] = (uint16_t)buf;
#undef STEP
}

// ---------------- K3a: fc2 for groups 0..11 (8 t per wave) -----------------
__global__ __launch_bounds__(256) void k_fc2a(const uint32_t* __restrict__ spk,
                                              const uint16_t* __restrict__ w2bf,
                                              const float* __restrict__ b2,
                                              float* __restrict__ cur2) {
  const int lane = threadIdx.x & 63, w = threadIdx.x >> 6;
  const int x = lane & 15, g = lane >> 4;
  const int wid = blockIdx.x * 4 + w;       // 0..3071
  const int gq = wid >> 8;                  // group 0..11
  const int bb = (wid & 255) << 5;          // 32 rows
  const uint16_t* wb = w2bf + (x << 10) + (g << 8);
  const uint32_t* s0 = spk + (((long)gq * NB + bb + x) << 8) + (g << 6);
  const uint32_t* s1 = s0 + (16 << 8);
  f32x4 acc[2][8];
#pragma unroll
  for (int i = 0; i < 2; ++i)
#pragma unroll
    for (int t = 0; t < 8; ++t) acc[i][t] = (f32x4){0, 0, 0, 0};

#pragma unroll 2
  for (int kc = 0; kc < 32; ++kc) {
    bf16x8 af = *(const bf16x8*)(wb + (kc << 3));
    uint2 d0 = *(const uint2*)(s0 + (kc << 1));
    uint2 d1 = *(const uint2*)(s1 + (kc << 1));
#pragma unroll
    for (int i = 0; i < 2; ++i) {
      uint2 d = i ? d1 : d0;
#pragma unroll
      for (int t = 0; t < 8; ++t) {
        uint32_t byte_ = ((d.x >> (4 * t)) & 0xFu) |
                         (((d.y >> (4 * t)) & 0xFu) << 4);
        union { uint32_t u[4]; bf16x8 v; } bf;
#pragma unroll
        for (int j = 0; j < 4; ++j) {
          uint32_t t2 = (byte_ >> (2 * j)) & 3u;
          uint32_t hb = (byte_ >> (2 * j + 1)) & 1u;
          bf.u[j] = (hb * 0xFFFEu + t2) * 0x3F80u;
        }
        acc[i][t] = __builtin_amdgcn_mfma_f32_16x16x32_bf16(af, bf.v,
                                                            acc[i][t], 0, 0, 0);
      }
    }
  }
  float bias[4];
#pragma unroll
  for (int r = 0; r < 4; ++r) {
    int o = (g << 2) + r;
    bias[r] = (o < NOUT) ? b2[o] : 0.0f;
  }
#pragma unroll
  for (int i = 0; i < 2; ++i) {
    long row = bb + (i << 4) + x;
#pragma unroll
    for (int t = 0; t < 8; ++t) {
      long tb = ((long)(gq * 8 + t) * NB + row) * NOUT;
#pragma unroll
      for (int r = 0; r < 4; ++r) {
        int o = (g << 2) + r;
        if (o < NOUT) cur2[tb + o] = acc[i][t][r] + bias[r];
      }
    }
  }
}

// ---------------- K3b: fc2 for t=96..99 (u16 tail layout) ------------------
__global__ __launch_bounds__(256) void k_fc2b(const uint32_t* __restrict__ spk16d,
                                              const uint16_t* __restrict__ w2bf,
                                              const float* __restrict__ b2,
                                              float* __restrict__ cur2) {
  const int lane = threadIdx.x & 63, w = threadIdx.x >> 6;
  const int x = lane & 15, g = lane >> 4;
  const int wid = blockIdx.x * 4 + w;       // 0..255
  const int bb = wid << 5;
  const uint16_t* wb = w2bf + (x << 10) + (g << 8);
  const uint32_t* s0 = spk16d + ((long)(bb + x) << 7) + (g << 5);
  const uint32_t* s1 = s0 + (16 << 7);
  f32x4 acc[2][4];
#pragma unroll
  for (int i = 0; i < 2; ++i)
#pragma unroll
    for (int t = 0; t < 4; ++t) acc[i][t] = (f32x4){0, 0, 0, 0};

#pragma unroll 2
  for (int kc = 0; kc < 32; ++kc) {
    bf16x8 af = *(const bf16x8*)(wb + (kc << 3));
    uint32_t d0 = s0[kc];
    uint32_t d1 = s1[kc];
#pragma unroll
    for (int i = 0; i < 2; ++i) {
      uint32_t d = i ? d1 : d0;
#pragma unroll
      for (int t = 0; t < 4; ++t) {
        uint32_t byte_ = ((d >> (4 * t)) & 0xFu) |
                         (((d >> (16 + 4 * t)) & 0xFu) << 4);
        union { uint32_t u[4]; bf16x8 v; } bf;
#pragma unroll
        for (int j = 0; j < 4; ++j) {
          uint32_t t2 = (byte_ >> (2 * j)) & 3u;
          uint32_t hb = (byte_ >> (2 * j + 1)) & 1u;
          bf.u[j] = (hb * 0xFFFEu + t2) * 0x3F80u;
        }
        acc[i][t] = __builtin_amdgcn_mfma_f32_16x16x32_bf16(af, bf.v,
                                                            acc[i][t], 0, 0, 0);
      }
    }
  }
  float bias[4];
#pragma unroll
  for (int r = 0; r < 4; ++r) {
    int o = (g << 2) + r;
    bias[r] = (o < NOUT) ? b2[o] : 0.0f;
  }
#pragma unroll
  for (int i = 0; i < 2; ++i) {
    long row = bb + (i << 4) + x;
#pragma unroll
    for (int t = 0; t < 4; ++t) {
      long tb = ((long)(96 + t) * NB + row) * NOUT;
#pragma unroll
      for (int r = 0; r < 4; ++r) {
        int o = (g << 2) + r;
        if (o < NOUT) cur2[tb + o] = acc[i][t][r] + bias[r];
      }
    }
  }
}

// ---------------- K4: LIF2 scan, 4-deep prefetch ---------------------------
__global__ __launch_bounds__(256) void k_lif2(float* io) {
  const int gid = blockIdx.x * 256 + threadIdx.x;   // < 81920
  float* sp = io + gid;
  float* mm = io + 8192000 + gid;
  float syn = 0.0f, mem = 0.0f;
  float c0 = sp[0], c1 = sp[81920], c2 = sp[2 * 81920], c3 = sp[3 * 81920];
  for (int t = 0; t < NT; t += 4) {
    float n0 = sp[(t + 4) * 81920], n1 = sp[(t + 5) * 81920];
    float n2 = sp[(t + 6) * 81920], n3 = sp[(t + 7) * 81920];
#define L2STEP(TT, CC)                                   \
    {                                                    \
      syn = fmaf(0.9f, syn, CC);                         \
      float r = (mem > 1.0f) ? 1.0f : 0.0f;              \
      mem = fmaf(0.85f, mem, syn) - r;                   \
      sp[(t + TT) * 81920] = (mem > 1.0f) ? 1.0f : 0.0f; \
      mm[(t + TT) * 81920] = mem;                        \
    }
    L2STEP(0, c0) L2STEP(1, c1) L2STEP(2, c2) L2STEP(3, c3)
#undef L2STEP
    c0 = n0; c1 = n1; c2 = n2; c3 = n3;
  }
}

extern "C" void kernel_launch(void* const* d_in, const int* in_sizes, int n_in,
                              void* d_out, int out_size, void* d_ws, size_t ws_size,
                              hipStream_t stream) {
  const float* x  = (const float*)d_in[0];
  const float* W1 = (const float*)d_in[1];
  const float* b1 = (const float*)d_in[2];
  const float* W2 = (const float*)d_in[3];
  const float* b2 = (const float*)d_in[4];
  float* out = (float*)d_out;
  float* memhalf = out + 8192000;                          // cur1 / mem_rec

  uint32_t* spk32 = (uint32_t*)d_ws;                       // 100663296 B
  uint32_t* spk16d = (uint32_t*)((char*)d_ws + 100663296); // 4194304 B
  uint16_t* spk16 = (uint16_t*)spk16d;
  uint16_t* w2bf = (uint16_t*)((char*)d_ws + 104857600);   // 32768 B

  uint16_t* xh = (uint16_t*)d_out;                         // staging in spk half
  uint16_t* xl = (uint16_t*)((char*)d_out + 13107200);
  uint16_t* wh = (uint16_t*)((char*)d_out + 26214400);
  uint16_t* wl = (uint16_t*)((char*)d_out + 27852800);

  k_w2bf<<<64, 256, 0, stream>>>(W2, w2bf);
  k_split<<<25600, 256, 0, stream>>>(x, xh, xl, NB, NB * KP);
  k_split<<<3200, 256, 0, stream>>>(W1, wh, wl, NH, NHP * KP);
  dim3 gg(128, 4);
  k_gemm1m<<<gg, 256, 0, stream>>>(xh, xl, wh, wl, b1, memhalf);
  k_lif1<<<NB, 256, 0, stream>>>(memhalf, spk32, spk16);
  k_fc2a<<<768, 256, 0, stream>>>(spk32, w2bf, b2, out);
  k_fc2b<<<64, 256, 0, stream>>>(spk16d, w2bf, b2, out);
  k_lif2<<<320, 256, 0, stream>>>(out);
}

// Round 7
// 341.930 us; speedup vs baseline: 2.1844x; 1.0123x over previous
//
#include <hip/hip_runtime.h>
#include <stdint.h>

#define NB   8192
#define NIN  784
#define KP   800       // K padded to 25*32 for gemm1 MFMA
#define NH   1000
#define NHP  1024
#define NOUT 10
#define NT   100

typedef float v2f    __attribute__((ext_vector_type(2)));
typedef short bf16x8 __attribute__((ext_vector_type(8)));
typedef float f32x4  __attribute__((ext_vector_type(4)));

// ---------------------------------------------------------------------------
// d_ws: [0, 100663296)            spk32 [12][NB][256] u32  (groups g: t=8g..8g+7)
//       [100663296, 104857600)    spk16 [NB][256] u16      (t=96..99, nibbles 0..3)
//       [104857600, +32768)       w2bf  [16][1024] bf16
// d_out spk half [0, 8192000 floats): staging xh[8192][800]bf16 @0B,
//       xl @13107200B, wh[1024][800] @26214400B, wl @27852800B  (cur2 later)
// d_out mem half: cur1 [8192][1000] f32 (mem_rec later)
// spike dword [g][b][q]: nibble n bit j = spike(t=8g+n, h=4q+j)
// ---------------------------------------------------------------------------

__device__ __forceinline__ uint16_t f2bf(float v) {
  uint32_t x = __float_as_uint(v);
  return (uint16_t)((x + 0x7FFFu + ((x >> 16) & 1u)) >> 16);
}

// ---------------- K0: W2 -> bf16 [16][1024] --------------------------------
__global__ __launch_bounds__(256) void k_w2bf(const float* __restrict__ W2,
                                              uint16_t* __restrict__ w2bf) {
  int i = blockIdx.x * 256 + threadIdx.x;   // 16*1024
  int o = i >> 10, h = i & 1023;
  float v = (o < NOUT && h < NH) ? W2[o * NH + h] : 0.0f;
  w2bf[i] = f2bf(v);
}

// ---------------- K0b: split fp32 -> (bf16 hi, bf16 lo), zero-padded -------
__global__ __launch_bounds__(256) void k_split(const float* __restrict__ src,
                                               uint16_t* __restrict__ hi,
                                               uint16_t* __restrict__ lo,
                                               int rows_valid, int total) {
  int i = blockIdx.x * 256 + threadIdx.x;
  if (i >= total) return;
  int r = i / KP, k = i - r * KP;
  float v = (r < rows_valid && k < NIN) ? src[r * NIN + k] : 0.0f;
  uint16_t h = f2bf(v);
  float hv = __uint_as_float(((uint32_t)h) << 16);
  hi[i] = h;
  lo[i] = f2bf(v - hv);
}

// ---------------- K1: cur1 = x @ W1^T + b1, split-bf16 MFMA ----------------
__global__ __launch_bounds__(256) void k_gemm1m(
    const uint16_t* __restrict__ xh, const uint16_t* __restrict__ xl,
    const uint16_t* __restrict__ wh, const uint16_t* __restrict__ wl,
    const float* __restrict__ b1, float* __restrict__ C) {
  const int lane = threadIdx.x & 63, w = threadIdx.x >> 6;
  const int x = lane & 15, g = lane >> 4;
  const int m0 = blockIdx.x << 6;
  const int n0 = (blockIdx.y << 8) + (w << 6);
  long ar[4], br[4];
#pragma unroll
  for (int s = 0; s < 4; ++s) {
    ar[s] = (long)(m0 + s * 16 + x) * KP + (g << 3);
    br[s] = (long)(n0 + s * 16 + x) * KP + (g << 3);
  }
  f32x4 acc[4][4];
#pragma unroll
  for (int mt = 0; mt < 4; ++mt)
#pragma unroll
    for (int nt = 0; nt < 4; ++nt) acc[mt][nt] = (f32x4){0, 0, 0, 0};

  for (int kc = 0; kc < 25; ++kc) {
    const int ko = kc << 5;
    bf16x8 afh[4], afl[4], bfh[4], bfl[4];
#pragma unroll
    for (int s = 0; s < 4; ++s) {
      afh[s] = *(const bf16x8*)(xh + ar[s] + ko);
      afl[s] = *(const bf16x8*)(xl + ar[s] + ko);
      bfh[s] = *(const bf16x8*)(wh + br[s] + ko);
      bfl[s] = *(const bf16x8*)(wl + br[s] + ko);
    }
#pragma unroll
    for (int mt = 0; mt < 4; ++mt)
#pragma unroll
      for (int nt = 0; nt < 4; ++nt) {
        acc[mt][nt] = __builtin_amdgcn_mfma_f32_16x16x32_bf16(
            afh[mt], bfh[nt], acc[mt][nt], 0, 0, 0);
        acc[mt][nt] = __builtin_amdgcn_mfma_f32_16x16x32_bf16(
            afh[mt], bfl[nt], acc[mt][nt], 0, 0, 0);
        acc[mt][nt] = __builtin_amdgcn_mfma_f32_16x16x32_bf16(
            afl[mt], bfh[nt], acc[mt][nt], 0, 0, 0);
      }
  }
#pragma unroll
  for (int nt = 0; nt < 4; ++nt) {
    int n = n0 + (nt << 4) + x;
    if (n < NH) {
      float bias = b1[n];
#pragma unroll
      for (int mt = 0; mt < 4; ++mt)
#pragma unroll
        for (int r = 0; r < 4; ++r) {
          int m = m0 + (mt << 4) + (g << 2) + r;
          C[(long)m * NH + n] = acc[mt][nt][r] + bias;
        }
    }
  }
}

// ---------------- K2: LIF1 scan, float-rn state, arithmetic nibble ---------
// thread q owns h = 4q..4q+3 (2 v2f pairs). NO persistent bools (they cost
// rematerialize-cmp per use): the reset value rn in {0,-1} IS the state,
// computed by ternary while vcc is live. Nibble = -rn0-2rn1-4rn2-8rn3 via
// 3 v_fma (neg + inline-const mods) + cvt + lshl_or. ~19 VALU/step.
__global__ __launch_bounds__(256) void k_lif1(const float* __restrict__ cur1,
                                              uint32_t* __restrict__ spk32,
                                              uint16_t* __restrict__ spk16) {
  const int b = blockIdx.x, q = threadIdx.x;
  float4 c4 = {0, 0, 0, 0};
  if (q < 250) c4 = *(const float4*)(cur1 + (long)b * NH + (q << 2));
  v2f ca = {c4.x, c4.y}, cb = {c4.z, c4.w};
  v2f syna = {0, 0}, synb = {0, 0}, mema = {0, 0}, memb = {0, 0};
  v2f rna = {0, 0}, rnb = {0, 0};   // -1.0 if spiked last step, else 0.0
  const v2f k9 = {0.9f, 0.9f}, k85 = {0.85f, 0.85f};
  uint32_t* sp = spk32 + ((long)b << 8) + q;
  const long gstep = (long)NB << 8;
  uint32_t buf;
#define STEP(N)                                                             \
  {                                                                         \
    asm("v_pk_fma_f32 %0, %1, %0, %2" : "+v"(syna) : "v"(k9), "v"(ca));     \
    asm("v_pk_fma_f32 %0, %1, %0, %2" : "+v"(synb) : "v"(k9), "v"(cb));     \
    asm("v_pk_fma_f32 %0, %1, %0, %2" : "+v"(mema) : "v"(k85), "v"(syna));  \
    asm("v_pk_fma_f32 %0, %1, %0, %2" : "+v"(memb) : "v"(k85), "v"(synb));  \
    asm("v_pk_add_f32 %0, %0, %1" : "+v"(mema) : "v"(rna));                 \
    asm("v_pk_add_f32 %0, %0, %1" : "+v"(memb) : "v"(rnb));                 \
    rna.x = mema.x > 1.0f ? -1.0f : 0.0f;                                   \
    rna.y = mema.y > 1.0f ? -1.0f : 0.0f;                                   \
    rnb.x = memb.x > 1.0f ? -1.0f : 0.0f;                                   \
    rnb.y = memb.y > 1.0f ? -1.0f : 0.0f;                                   \
    float nf = fmaf(-2.0f, rna.y, -rna.x);                                  \
    nf = fmaf(-4.0f, rnb.x, nf);                                            \
    nf = fmaf(-8.0f, rnb.y, nf);                                            \
    buf |= ((uint32_t)nf) << (4 * (N));                                     \
  }
  for (int gi = 0; gi < 12; ++gi) {
    buf = 0;
    STEP(0) STEP(1) STEP(2) STEP(3) STEP(4) STEP(5) STEP(6) STEP(7)
    *sp = buf;  sp += gstep;
  }
  buf = 0;
  STEP(0) STEP(1) STEP(2) STEP(3)
  spk16[((long)b << 8) + q] = (uint16_t)buf;
#undef STEP
}

// ---------------- K3a: fc2 for groups 0..11 (8 t per wave) -----------------
// B-words built by direct bfe from the raw spike dwords (no byte assembly):
// word j<2 from d.x bits 4t+2j, j>=2 from d.y bits 4t+2(j-2).
__global__ __launch_bounds__(256) void k_fc2a(const uint32_t* __restrict__ spk,
                                              const uint16_t* __restrict__ w2bf,
                                              const float* __restrict__ b2,
                                              float* __restrict__ cur2) {
  const int lane = threadIdx.x & 63, w = threadIdx.x >> 6;
  const int x = lane & 15, g = lane >> 4;
  const int wid = blockIdx.x * 4 + w;       // 0..3071
  const int gq = wid >> 8;                  // group 0..11
  const int bb = (wid & 255) << 5;          // 32 rows
  const uint16_t* wb = w2bf + (x << 10) + (g << 8);
  const uint32_t* s0 = spk + (((long)gq * NB + bb + x) << 8) + (g << 6);
  const uint32_t* s1 = s0 + (16 << 8);
  f32x4 acc[2][8];
#pragma unroll
  for (int i = 0; i < 2; ++i)
#pragma unroll
    for (int t = 0; t < 8; ++t) acc[i][t] = (f32x4){0, 0, 0, 0};

#pragma unroll 2
  for (int kc = 0; kc < 32; ++kc) {
    bf16x8 af = *(const bf16x8*)(wb + (kc << 3));
    uint2 d0 = *(const uint2*)(s0 + (kc << 1));
    uint2 d1 = *(const uint2*)(s1 + (kc << 1));
#pragma unroll
    for (int i = 0; i < 2; ++i) {
      uint2 d = i ? d1 : d0;
#pragma unroll
      for (int t = 0; t < 8; ++t) {
        union { uint32_t u[4]; bf16x8 v; } bf;
#pragma unroll
        for (int j = 0; j < 4; ++j) {
          uint32_t src = (j < 2) ? d.x : d.y;
          int pos = 4 * t + 2 * (j & 1);
          uint32_t t2 = (src >> pos) & 3u;
          uint32_t hb = (src >> (pos + 1)) & 1u;
          bf.u[j] = (hb * 0xFFFEu + t2) * 0x3F80u;
        }
        acc[i][t] = __builtin_amdgcn_mfma_f32_16x16x32_bf16(af, bf.v,
                                                            acc[i][t], 0, 0, 0);
      }
    }
  }
  float bias[4];
#pragma unroll
  for (int r = 0; r < 4; ++r) {
    int o = (g << 2) + r;
    bias[r] = (o < NOUT) ? b2[o] : 0.0f;
  }
#pragma unroll
  for (int i = 0; i < 2; ++i) {
    long row = bb + (i << 4) + x;
#pragma unroll
    for (int t = 0; t < 8; ++t) {
      long tb = ((long)(gq * 8 + t) * NB + row) * NOUT;
#pragma unroll
      for (int r = 0; r < 4; ++r) {
        int o = (g << 2) + r;
        if (o < NOUT) cur2[tb + o] = acc[i][t][r] + bias[r];
      }
    }
  }
}

// ---------------- K3b: fc2 for t=96..99 (u16 tail layout) ------------------
__global__ __launch_bounds__(256) void k_fc2b(const uint32_t* __restrict__ spk16d,
                                              const uint16_t* __restrict__ w2bf,
                                              const float* __restrict__ b2,
                                              float* __restrict__ cur2) {
  const int lane = threadIdx.x & 63, w = threadIdx.x >> 6;
  const int x = lane & 15, g = lane >> 4;
  const int wid = blockIdx.x * 4 + w;       // 0..255
  const int bb = wid << 5;
  const uint16_t* wb = w2bf + (x << 10) + (g << 8);
  const uint32_t* s0 = spk16d + ((long)(bb + x) << 7) + (g << 5);
  const uint32_t* s1 = s0 + (16 << 7);
  f32x4 acc[2][4];
#pragma unroll
  for (int i = 0; i < 2; ++i)
#pragma unroll
    for (int t = 0; t < 4; ++t) acc[i][t] = (f32x4){0, 0, 0, 0};

#pragma unroll 2
  for (int kc = 0; kc < 32; ++kc) {
    bf16x8 af = *(const bf16x8*)(wb + (kc << 3));
    uint32_t d0 = s0[kc];
    uint32_t d1 = s1[kc];
#pragma unroll
    for (int i = 0; i < 2; ++i) {
      uint32_t d = i ? d1 : d0;
#pragma unroll
      for (int t = 0; t < 4; ++t) {
        union { uint32_t u[4]; bf16x8 v; } bf;
#pragma unroll
        for (int j = 0; j < 4; ++j) {
          int pos = 4 * t + 2 * (j & 1) + ((j >> 1) << 4);
          uint32_t t2 = (d >> pos) & 3u;
          uint32_t hb = (d >> (pos + 1)) & 1u;
          bf.u[j] = (hb * 0xFFFEu + t2) * 0x3F80u;
        }
        acc[i][t] = __builtin_amdgcn_mfma_f32_16x16x32_bf16(af, bf.v,
                                                            acc[i][t], 0, 0, 0);
      }
    }
  }
  float bias[4];
#pragma unroll
  for (int r = 0; r < 4; ++r) {
    int o = (g << 2) + r;
    bias[r] = (o < NOUT) ? b2[o] : 0.0f;
  }
#pragma unroll
  for (int i = 0; i < 2; ++i) {
    long row = bb + (i << 4) + x;
#pragma unroll
    for (int t = 0; t < 4; ++t) {
      long tb = ((long)(96 + t) * NB + row) * NOUT;
#pragma unroll
      for (int r = 0; r < 4; ++r) {
        int o = (g << 2) + r;
        if (o < NOUT) cur2[tb + o] = acc[i][t][r] + bias[r];
      }
    }
  }
}

// ---------------- K4: LIF2 scan, 4-deep prefetch ---------------------------
__global__ __launch_bounds__(256) void k_lif2(float* io) {
  const int gid = blockIdx.x * 256 + threadIdx.x;   // < 81920
  float* sp = io + gid;
  float* mm = io + 8192000 + gid;
  float syn = 0.0f, mem = 0.0f;
  float c0 = sp[0], c1 = sp[81920], c2 = sp[2 * 81920], c3 = sp[3 * 81920];
  for (int t = 0; t < NT; t += 4) {
    float n0 = sp[(t + 4) * 81920], n1 = sp[(t + 5) * 81920];
    float n2 = sp[(t + 6) * 81920], n3 = sp[(t + 7) * 81920];
#define L2STEP(TT, CC)                                   \
    {                                                    \
      syn = fmaf(0.9f, syn, CC);                         \
      float r = (mem > 1.0f) ? 1.0f : 0.0f;              \
      mem = fmaf(0.85f, mem, syn) - r;                   \
      sp[(t + TT) * 81920] = (mem > 1.0f) ? 1.0f : 0.0f; \
      mm[(t + TT) * 81920] = mem;                        \
    }
    L2STEP(0, c0) L2STEP(1, c1) L2STEP(2, c2) L2STEP(3, c3)
#undef L2STEP
    c0 = n0; c1 = n1; c2 = n2; c3 = n3;
  }
}

extern "C" void kernel_launch(void* const* d_in, const int* in_sizes, int n_in,
                              void* d_out, int out_size, void* d_ws, size_t ws_size,
                              hipStream_t stream) {
  const float* x  = (const float*)d_in[0];
  const float* W1 = (const float*)d_in[1];
  const float* b1 = (const float*)d_in[2];
  const float* W2 = (const float*)d_in[3];
  const float* b2 = (const float*)d_in[4];
  float* out = (float*)d_out;
  float* memhalf = out + 8192000;                          // cur1 / mem_rec

  uint32_t* spk32 = (uint32_t*)d_ws;                       // 100663296 B
  uint32_t* spk16d = (uint32_t*)((char*)d_ws + 100663296); // 4194304 B
  uint16_t* spk16 = (uint16_t*)spk16d;
  uint16_t* w2bf = (uint16_t*)((char*)d_ws + 104857600);   // 32768 B

  uint16_t* xh = (uint16_t*)d_out;                         // staging in spk half
  uint16_t* xl = (uint16_t*)((char*)d_out + 13107200);
  uint16_t* wh = (uint16_t*)((char*)d_out + 26214400);
  uint16_t* wl = (uint16_t*)((char*)d_out + 27852800);

  k_w2bf<<<64, 256, 0, stream>>>(W2, w2bf);
  k_split<<<25600, 256, 0, stream>>>(x, xh, xl, NB, NB * KP);
  k_split<<<3200, 256, 0, stream>>>(W1, wh, wl, NH, NHP * KP);
  dim3 gg(128, 4);
  k_gemm1m<<<gg, 256, 0, stream>>>(xh, xl, wh, wl, b1, memhalf);
  k_lif1<<<NB, 256, 0, stream>>>(memhalf, spk32, spk16);
  k_fc2a<<<768, 256, 0, stream>>>(spk32, w2bf, b2, out);
  k_fc2b<<<64, 256, 0, stream>>>(spk16d, w2bf, b2, out);
  k_lif2<<<320, 256, 0, stream>>>(out);
}

// Round 8
// 309.467 us; speedup vs baseline: 2.4136x; 1.1049x over previous
//
#include <hip/hip_runtime.h>
#include <stdint.h>

#define NB   8192
#define NIN  784
#define KP   800       // K padded to 25*32 for gemm1 MFMA
#define NH   1000
#define NHP  1024
#define NOUT 10
#define NT   100

typedef float v2f    __attribute__((ext_vector_type(2)));
typedef short bf16x8 __attribute__((ext_vector_type(8)));
typedef float f32x4  __attribute__((ext_vector_type(4)));

// ---------------------------------------------------------------------------
// d_ws: [0, 100663296)            spk32 [12][NB][256] u32  (groups g: t=8g..8g+7)
//       [100663296, 104857600)    spk16 [NB][256] u16      (t=96..99, nibbles 0..3)
//       [104857600, +32768)       w2bf  [16][1024] bf16
// d_out spk half [0, 8192000 floats): staging xh[8192][800]bf16 @0B,
//       xl @13107200B, wh[1024][800] @26214400B, wl @27852800B  (cur2 later)
// d_out mem half: cur1 [8192][1000] f32 (mem_rec later)
// spike dword [g][b][q]: nibble n bit j = spike(t=8g+n, h=4q+j)
// ---------------------------------------------------------------------------

__device__ __forceinline__ uint16_t f2bf(float v) {
  uint32_t x = __float_as_uint(v);
  return (uint16_t)((x + 0x7FFFu + ((x >> 16) & 1u)) >> 16);
}

// ---------------- K0: W2 -> bf16 [16][1024] --------------------------------
__global__ __launch_bounds__(256) void k_w2bf(const float* __restrict__ W2,
                                              uint16_t* __restrict__ w2bf) {
  int i = blockIdx.x * 256 + threadIdx.x;   // 16*1024
  int o = i >> 10, h = i & 1023;
  float v = (o < NOUT && h < NH) ? W2[o * NH + h] : 0.0f;
  w2bf[i] = f2bf(v);
}

// ---------------- K0b: split fp32 -> (bf16 hi, bf16 lo), zero-padded -------
__global__ __launch_bounds__(256) void k_split(const float* __restrict__ src,
                                               uint16_t* __restrict__ hi,
                                               uint16_t* __restrict__ lo,
                                               int rows_valid, int total) {
  int i = blockIdx.x * 256 + threadIdx.x;
  if (i >= total) return;
  int r = i / KP, k = i - r * KP;
  float v = (r < rows_valid && k < NIN) ? src[r * NIN + k] : 0.0f;
  uint16_t h = f2bf(v);
  float hv = __uint_as_float(((uint32_t)h) << 16);
  hi[i] = h;
  lo[i] = f2bf(v - hv);
}

// ---------------- K1: cur1 = x @ W1^T + b1, split-bf16 MFMA ----------------
__global__ __launch_bounds__(256) void k_gemm1m(
    const uint16_t* __restrict__ xh, const uint16_t* __restrict__ xl,
    const uint16_t* __restrict__ wh, const uint16_t* __restrict__ wl,
    const float* __restrict__ b1, float* __restrict__ C) {
  const int lane = threadIdx.x & 63, w = threadIdx.x >> 6;
  const int x = lane & 15, g = lane >> 4;
  const int m0 = blockIdx.x << 6;
  const int n0 = (blockIdx.y << 8) + (w << 6);
  long ar[4], br[4];
#pragma unroll
  for (int s = 0; s < 4; ++s) {
    ar[s] = (long)(m0 + s * 16 + x) * KP + (g << 3);
    br[s] = (long)(n0 + s * 16 + x) * KP + (g << 3);
  }
  f32x4 acc[4][4];
#pragma unroll
  for (int mt = 0; mt < 4; ++mt)
#pragma unroll
    for (int nt = 0; nt < 4; ++nt) acc[mt][nt] = (f32x4){0, 0, 0, 0};

  for (int kc = 0; kc < 25; ++kc) {
    const int ko = kc << 5;
    bf16x8 afh[4], afl[4], bfh[4], bfl[4];
#pragma unroll
    for (int s = 0; s < 4; ++s) {
      afh[s] = *(const bf16x8*)(xh + ar[s] + ko);
      afl[s] = *(const bf16x8*)(xl + ar[s] + ko);
      bfh[s] = *(const bf16x8*)(wh + br[s] + ko);
      bfl[s] = *(const bf16x8*)(wl + br[s] + ko);
    }
#pragma unroll
    for (int mt = 0; mt < 4; ++mt)
#pragma unroll
      for (int nt = 0; nt < 4; ++nt) {
        acc[mt][nt] = __builtin_amdgcn_mfma_f32_16x16x32_bf16(
            afh[mt], bfh[nt], acc[mt][nt], 0, 0, 0);
        acc[mt][nt] = __builtin_amdgcn_mfma_f32_16x16x32_bf16(
            afh[mt], bfl[nt], acc[mt][nt], 0, 0, 0);
        acc[mt][nt] = __builtin_amdgcn_mfma_f32_16x16x32_bf16(
            afl[mt], bfh[nt], acc[mt][nt], 0, 0, 0);
      }
  }
#pragma unroll
  for (int nt = 0; nt < 4; ++nt) {
    int n = n0 + (nt << 4) + x;
    if (n < NH) {
      float bias = b1[n];
#pragma unroll
      for (int mt = 0; mt < 4; ++mt)
#pragma unroll
        for (int r = 0; r < 4; ++r) {
          int m = m0 + (mt << 4) + (g << 2) + r;
          C[(long)m * NH + n] = acc[mt][nt][r] + bias;
        }
    }
  }
}

// ---------------- K2: LIF1 scan, exact-25-instr asm step -------------------
// thread q owns h = 4q..4q+3, scalar f32 (v_pk_* f32 ops are NOT faster:
// same 32-wide f32 pipe; R5-R7 all ~85cy/step regardless). One asm block
// pins the step to 25 VOPs: 4 syn-fma, 4 add(syn+rn), 4 mem-fma, 4 cmp/
// cndmask (rn in {0,-1} is the persistent state), 5-op nibble pack.
__global__ __launch_bounds__(256) void k_lif1(const float* __restrict__ cur1,
                                              uint32_t* __restrict__ spk32,
                                              uint16_t* __restrict__ spk16) {
  const int b = blockIdx.x, q = threadIdx.x;
  float4 c4 = {0, 0, 0, 0};
  if (q < 250) c4 = *(const float4*)(cur1 + (long)b * NH + (q << 2));
  float s0 = 0, s1 = 0, s2 = 0, s3 = 0;
  float m0 = 0, m1 = 0, m2 = 0, m3 = 0;
  float r0 = 0, r1 = 0, r2 = 0, r3 = 0;   // -1.0 if spiked last step
  const float k9 = 0.9f, k85 = 0.85f, n1 = -1.0f;
  uint32_t* sp = spk32 + ((long)b << 8) + q;
  const long gstep = (long)NB << 8;
  uint32_t buf;
#define STEP(SH, BUF)                                                       \
  {                                                                         \
    float t0, t1, x0, x1, x2, x3;                                           \
    asm("v_fma_f32 %[s0], %[k9], %[s0], %[c0]\n\t"                          \
        "v_fma_f32 %[s1], %[k9], %[s1], %[c1]\n\t"                          \
        "v_fma_f32 %[s2], %[k9], %[s2], %[c2]\n\t"                          \
        "v_fma_f32 %[s3], %[k9], %[s3], %[c3]\n\t"                          \
        "v_add_f32 %[x0], %[s0], %[r0]\n\t"                                 \
        "v_add_f32 %[x1], %[s1], %[r1]\n\t"                                 \
        "v_add_f32 %[x2], %[s2], %[r2]\n\t"                                 \
        "v_add_f32 %[x3], %[s3], %[r3]\n\t"                                 \
        "v_fma_f32 %[m0], %[k85], %[m0], %[x0]\n\t"                         \
        "v_fma_f32 %[m1], %[k85], %[m1], %[x1]\n\t"                         \
        "v_fma_f32 %[m2], %[k85], %[m2], %[x2]\n\t"                         \
        "v_fma_f32 %[m3], %[k85], %[m3], %[x3]\n\t"                         \
        "v_cmp_lt_f32 vcc, 1.0, %[m0]\n\t"                                  \
        "v_cndmask_b32 %[r0], 0, %[n1], vcc\n\t"                            \
        "v_cmp_lt_f32 vcc, 1.0, %[m1]\n\t"                                  \
        "v_cndmask_b32 %[r1], 0, %[n1], vcc\n\t"                            \
        "v_cmp_lt_f32 vcc, 1.0, %[m2]\n\t"                                  \
        "v_cndmask_b32 %[r2], 0, %[n1], vcc\n\t"                            \
        "v_cmp_lt_f32 vcc, 1.0, %[m3]\n\t"                                  \
        "v_cndmask_b32 %[r3], 0, %[n1], vcc\n\t"                            \
        "v_fma_f32 %[t0], %[r1], -2.0, -%[r0]\n\t"                          \
        "v_fma_f32 %[t1], %[r3], -2.0, -%[r2]\n\t"                          \
        "v_fma_f32 %[t0], %[t1], 4.0, %[t0]\n\t"                            \
        "v_cvt_u32_f32 %[t1], %[t0]\n\t"                                    \
        "v_lshl_or_b32 %[buf], %[t1], " #SH ", %[buf]"                      \
        : [s0] "+v"(s0), [s1] "+v"(s1), [s2] "+v"(s2), [s3] "+v"(s3),       \
          [m0] "+v"(m0), [m1] "+v"(m1), [m2] "+v"(m2), [m3] "+v"(m3),       \
          [r0] "+v"(r0), [r1] "+v"(r1), [r2] "+v"(r2), [r3] "+v"(r3),       \
          [buf] "+v"(BUF), [t0] "=&v"(t0), [t1] "=&v"(t1),                  \
          [x0] "=&v"(x0), [x1] "=&v"(x1), [x2] "=&v"(x2), [x3] "=&v"(x3)    \
        : [c0] "v"(c4.x), [c1] "v"(c4.y), [c2] "v"(c4.z), [c3] "v"(c4.w),   \
          [k9] "v"(k9), [k85] "v"(k85), [n1] "v"(n1)                        \
        : "vcc");                                                           \
  }
  uint32_t bufA = 0, bufB = 0;
  for (int gi = 0; gi < 6; ++gi) {   // 6 x 16 steps = 96
    bufA = 0;
    STEP(0, bufA) STEP(4, bufA) STEP(8, bufA) STEP(12, bufA)
    STEP(16, bufA) STEP(20, bufA) STEP(24, bufA) STEP(28, bufA)
    *sp = bufA;  sp += gstep;
    bufB = 0;
    STEP(0, bufB) STEP(4, bufB) STEP(8, bufB) STEP(12, bufB)
    STEP(16, bufB) STEP(20, bufB) STEP(24, bufB) STEP(28, bufB)
    *sp = bufB;  sp += gstep;
  }
  bufA = 0;
  STEP(0, bufA) STEP(4, bufA) STEP(8, bufA) STEP(12, bufA)
  spk16[((long)b << 8) + q] = (uint16_t)bufA;
#undef STEP
}

// ---------------- K3a: fc2 for groups 0..11 (8 t per wave) -----------------
__global__ __launch_bounds__(256) void k_fc2a(const uint32_t* __restrict__ spk,
                                              const uint16_t* __restrict__ w2bf,
                                              const float* __restrict__ b2,
                                              float* __restrict__ cur2) {
  const int lane = threadIdx.x & 63, w = threadIdx.x >> 6;
  const int x = lane & 15, g = lane >> 4;
  const int wid = blockIdx.x * 4 + w;       // 0..3071
  const int gq = wid >> 8;                  // group 0..11
  const int bb = (wid & 255) << 5;          // 32 rows
  const uint16_t* wb = w2bf + (x << 10) + (g << 8);
  const uint32_t* s0 = spk + (((long)gq * NB + bb + x) << 8) + (g << 6);
  const uint32_t* s1 = s0 + (16 << 8);
  f32x4 acc[2][8];
#pragma unroll
  for (int i = 0; i < 2; ++i)
#pragma unroll
    for (int t = 0; t < 8; ++t) acc[i][t] = (f32x4){0, 0, 0, 0};

#pragma unroll 2
  for (int kc = 0; kc < 32; ++kc) {
    bf16x8 af = *(const bf16x8*)(wb + (kc << 3));
    uint2 d0 = *(const uint2*)(s0 + (kc << 1));
    uint2 d1 = *(const uint2*)(s1 + (kc << 1));
#pragma unroll
    for (int i = 0; i < 2; ++i) {
      uint2 d = i ? d1 : d0;
#pragma unroll
      for (int t = 0; t < 8; ++t) {
        union { uint32_t u[4]; bf16x8 v; } bf;
#pragma unroll
        for (int j = 0; j < 4; ++j) {
          uint32_t src = (j < 2) ? d.x : d.y;
          int pos = 4 * t + 2 * (j & 1);
          uint32_t t2 = (src >> pos) & 3u;
          uint32_t hb = (src >> (pos + 1)) & 1u;
          bf.u[j] = (hb * 0xFFFEu + t2) * 0x3F80u;
        }
        acc[i][t] = __builtin_amdgcn_mfma_f32_16x16x32_bf16(af, bf.v,
                                                            acc[i][t], 0, 0, 0);
      }
    }
  }
  float bias[4];
#pragma unroll
  for (int r = 0; r < 4; ++r) {
    int o = (g << 2) + r;
    bias[r] = (o < NOUT) ? b2[o] : 0.0f;
  }
#pragma unroll
  for (int i = 0; i < 2; ++i) {
    long row = bb + (i << 4) + x;
#pragma unroll
    for (int t = 0; t < 8; ++t) {
      long tb = ((long)(gq * 8 + t) * NB + row) * NOUT;
#pragma unroll
      for (int r = 0; r < 4; ++r) {
        int o = (g << 2) + r;
        if (o < NOUT) cur2[tb + o] = acc[i][t][r] + bias[r];
      }
    }
  }
}

// ---------------- K3b: fc2 for t=96..99 (u16 tail layout) ------------------
__global__ __launch_bounds__(256) void k_fc2b(const uint32_t* __restrict__ spk16d,
                                              const uint16_t* __restrict__ w2bf,
                                              const float* __restrict__ b2,
                                              float* __restrict__ cur2) {
  const int lane = threadIdx.x & 63, w = threadIdx.x >> 6;
  const int x = lane & 15, g = lane >> 4;
  const int wid = blockIdx.x * 4 + w;       // 0..255
  const int bb = wid << 5;
  const uint16_t* wb = w2bf + (x << 10) + (g << 8);
  const uint32_t* s0 = spk16d + ((long)(bb + x) << 7) + (g << 5);
  const uint32_t* s1 = s0 + (16 << 7);
  f32x4 acc[2][4];
#pragma unroll
  for (int i = 0; i < 2; ++i)
#pragma unroll
    for (int t = 0; t < 4; ++t) acc[i][t] = (f32x4){0, 0, 0, 0};

#pragma unroll 2
  for (int kc = 0; kc < 32; ++kc) {
    bf16x8 af = *(const bf16x8*)(wb + (kc << 3));
    uint32_t d0 = s0[kc];
    uint32_t d1 = s1[kc];
#pragma unroll
    for (int i = 0; i < 2; ++i) {
      uint32_t d = i ? d1 : d0;
#pragma unroll
      for (int t = 0; t < 4; ++t) {
        union { uint32_t u[4]; bf16x8 v; } bf;
#pragma unroll
        for (int j = 0; j < 4; ++j) {
          int pos = 4 * t + 2 * (j & 1) + ((j >> 1) << 4);
          uint32_t t2 = (d >> pos) & 3u;
          uint32_t hb = (d >> (pos + 1)) & 1u;
          bf.u[j] = (hb * 0xFFFEu + t2) * 0x3F80u;
        }
        acc[i][t] = __builtin_amdgcn_mfma_f32_16x16x32_bf16(af, bf.v,
                                                            acc[i][t], 0, 0, 0);
      }
    }
  }
  float bias[4];
#pragma unroll
  for (int r = 0; r < 4; ++r) {
    int o = (g << 2) + r;
    bias[r] = (o < NOUT) ? b2[o] : 0.0f;
  }
#pragma unroll
  for (int i = 0; i < 2; ++i) {
    long row = bb + (i << 4) + x;
#pragma unroll
    for (int t = 0; t < 4; ++t) {
      long tb = ((long)(96 + t) * NB + row) * NOUT;
#pragma unroll
      for (int r = 0; r < 4; ++r) {
        int o = (g << 2) + r;
        if (o < NOUT) cur2[tb + o] = acc[i][t][r] + bias[r];
      }
    }
  }
}

// ---------------- K4: LIF2 scan, 4-deep prefetch ---------------------------
__global__ __launch_bounds__(256) void k_lif2(float* io) {
  const int gid = blockIdx.x * 256 + threadIdx.x;   // < 81920
  float* sp = io + gid;
  float* mm = io + 8192000 + gid;
  float syn = 0.0f, mem = 0.0f;
  float c0 = sp[0], c1 = sp[81920], c2 = sp[2 * 81920], c3 = sp[3 * 81920];
  for (int t = 0; t < NT; t += 4) {
    float n0 = sp[(t + 4) * 81920], n1 = sp[(t + 5) * 81920];
    float n2 = sp[(t + 6) * 81920], n3 = sp[(t + 7) * 81920];
#define L2STEP(TT, CC)                                   \
    {                                                    \
      syn = fmaf(0.9f, syn, CC);                         \
      float r = (mem > 1.0f) ? 1.0f : 0.0f;              \
      mem = fmaf(0.85f, mem, syn) - r;                   \
      sp[(t + TT) * 81920] = (mem > 1.0f) ? 1.0f : 0.0f; \
      mm[(t + TT) * 81920] = mem;                        \
    }
    L2STEP(0, c0) L2STEP(1, c1) L2STEP(2, c2) L2STEP(3, c3)
#undef L2STEP
    c0 = n0; c1 = n1; c2 = n2; c3 = n3;
  }
}

extern "C" void kernel_launch(void* const* d_in, const int* in_sizes, int n_in,
                              void* d_out, int out_size, void* d_ws, size_t ws_size,
                              hipStream_t stream) {
  const float* x  = (const float*)d_in[0];
  const float* W1 = (const float*)d_in[1];
  const float* b1 = (const float*)d_in[2];
  const float* W2 = (const float*)d_in[3];
  const float* b2 = (const float*)d_in[4];
  float* out = (float*)d_out;
  float* memhalf = out + 8192000;                          // cur1 / mem_rec

  uint32_t* spk32 = (uint32_t*)d_ws;                       // 100663296 B
  uint32_t* spk16d = (uint32_t*)((char*)d_ws + 100663296); // 4194304 B
  uint16_t* spk16 = (uint16_t*)spk16d;
  uint16_t* w2bf = (uint16_t*)((char*)d_ws + 104857600);   // 32768 B

  uint16_t* xh = (uint16_t*)d_out;                         // staging in spk half
  uint16_t* xl = (uint16_t*)((char*)d_out + 13107200);
  uint16_t* wh = (uint16_t*)((char*)d_out + 26214400);
  uint16_t* wl = (uint16_t*)((char*)d_out + 27852800);

  k_w2bf<<<64, 256, 0, stream>>>(W2, w2bf);
  k_split<<<25600, 256, 0, stream>>>(x, xh, xl, NB, NB * KP);
  k_split<<<3200, 256, 0, stream>>>(W1, wh, wl, NH, NHP * KP);
  dim3 gg(128, 4);
  k_gemm1m<<<gg, 256, 0, stream>>>(xh, xl, wh, wl, b1, memhalf);
  k_lif1<<<NB, 256, 0, stream>>>(memhalf, spk32, spk16);
  k_fc2a<<<768, 256, 0, stream>>>(spk32, w2bf, b2, out);
  k_fc2b<<<64, 256, 0, stream>>>(spk16d, w2bf, b2, out);
  k_lif2<<<320, 256, 0, stream>>>(out);
}

// Round 9
// 282.843 us; speedup vs baseline: 2.6408x; 1.0941x over previous
//
#include <hip/hip_runtime.h>
#include <stdint.h>

#define NB   8192
#define NIN  784
#define KP   800       // K padded to 25*32 for gemm1 MFMA
#define NH   1000
#define NHP  1024
#define NOUT 10
#define NT   100

typedef float v2f    __attribute__((ext_vector_type(2)));
typedef short bf16x8 __attribute__((ext_vector_type(8)));
typedef float f32x4  __attribute__((ext_vector_type(4)));

// ---------------------------------------------------------------------------
// d_ws: [0, 100663296)            spk32 [12][NB][256] u32  (groups g: t=8g..8g+7)
//       [100663296, 104857600)    spk16 [NB][256] u16      (t=96..99, nibbles 0..3)
//       [104857600, +32768)       w2bf  [16][1024] bf16
// d_out spk half [0, 8192000 floats): staging xh[8192][800]bf16 @0B,
//       xl @13107200B, wh[1024][800] @26214400B, wl @27852800B  (cur2 later)
// d_out mem half: cur1 [8192][1000] f32 (mem_rec later)
// spike dword [g][b][q]: nibble n bit j = spike(t=8g+n, h=4q+j)
// ---------------------------------------------------------------------------

__device__ __forceinline__ uint16_t f2bf(float v) {
  uint32_t x = __float_as_uint(v);
  return (uint16_t)((x + 0x7FFFu + ((x >> 16) & 1u)) >> 16);
}

// ---------------- K0: W2 -> bf16 [16][1024] --------------------------------
__global__ __launch_bounds__(256) void k_w2bf(const float* __restrict__ W2,
                                              uint16_t* __restrict__ w2bf) {
  int i = blockIdx.x * 256 + threadIdx.x;   // 16*1024
  int o = i >> 10, h = i & 1023;
  float v = (o < NOUT && h < NH) ? W2[o * NH + h] : 0.0f;
  w2bf[i] = f2bf(v);
}

// ---------------- K0b: split fp32 -> (bf16 hi, bf16 lo), zero-padded -------
__global__ __launch_bounds__(256) void k_split(const float* __restrict__ src,
                                               uint16_t* __restrict__ hi,
                                               uint16_t* __restrict__ lo,
                                               int rows_valid, int total) {
  int i = blockIdx.x * 256 + threadIdx.x;
  if (i >= total) return;
  int r = i / KP, k = i - r * KP;
  float v = (r < rows_valid && k < NIN) ? src[r * NIN + k] : 0.0f;
  uint16_t h = f2bf(v);
  float hv = __uint_as_float(((uint32_t)h) << 16);
  hi[i] = h;
  lo[i] = f2bf(v - hv);
}

// ---------------- K1: cur1 = x @ W1^T + b1, split-bf16 MFMA ----------------
__global__ __launch_bounds__(256) void k_gemm1m(
    const uint16_t* __restrict__ xh, const uint16_t* __restrict__ xl,
    const uint16_t* __restrict__ wh, const uint16_t* __restrict__ wl,
    const float* __restrict__ b1, float* __restrict__ C) {
  const int lane = threadIdx.x & 63, w = threadIdx.x >> 6;
  const int x = lane & 15, g = lane >> 4;
  const int m0 = blockIdx.x << 6;
  const int n0 = (blockIdx.y << 8) + (w << 6);
  long ar[4], br[4];
#pragma unroll
  for (int s = 0; s < 4; ++s) {
    ar[s] = (long)(m0 + s * 16 + x) * KP + (g << 3);
    br[s] = (long)(n0 + s * 16 + x) * KP + (g << 3);
  }
  f32x4 acc[4][4];
#pragma unroll
  for (int mt = 0; mt < 4; ++mt)
#pragma unroll
    for (int nt = 0; nt < 4; ++nt) acc[mt][nt] = (f32x4){0, 0, 0, 0};

  for (int kc = 0; kc < 25; ++kc) {
    const int ko = kc << 5;
    bf16x8 afh[4], afl[4], bfh[4], bfl[4];
#pragma unroll
    for (int s = 0; s < 4; ++s) {
      afh[s] = *(const bf16x8*)(xh + ar[s] + ko);
      afl[s] = *(const bf16x8*)(xl + ar[s] + ko);
      bfh[s] = *(const bf16x8*)(wh + br[s] + ko);
      bfl[s] = *(const bf16x8*)(wl + br[s] + ko);
    }
#pragma unroll
    for (int mt = 0; mt < 4; ++mt)
#pragma unroll
      for (int nt = 0; nt < 4; ++nt) {
        acc[mt][nt] = __builtin_amdgcn_mfma_f32_16x16x32_bf16(
            afh[mt], bfh[nt], acc[mt][nt], 0, 0, 0);
        acc[mt][nt] = __builtin_amdgcn_mfma_f32_16x16x32_bf16(
            afh[mt], bfl[nt], acc[mt][nt], 0, 0, 0);
        acc[mt][nt] = __builtin_amdgcn_mfma_f32_16x16x32_bf16(
            afl[mt], bfh[nt], acc[mt][nt], 0, 0, 0);
      }
  }
#pragma unroll
  for (int nt = 0; nt < 4; ++nt) {
    int n = n0 + (nt << 4) + x;
    if (n < NH) {
      float bias = b1[n];
#pragma unroll
      for (int mt = 0; mt < 4; ++mt)
#pragma unroll
        for (int r = 0; r < 4; ++r) {
          int m = m0 + (mt << 4) + (g << 2) + r;
          C[(long)m * NH + n] = acc[mt][nt][r] + bias;
        }
    }
  }
}

// ---------------- K2: LIF1 scan, exact-25-instr asm step -------------------
__global__ __launch_bounds__(256) void k_lif1(const float* __restrict__ cur1,
                                              uint32_t* __restrict__ spk32,
                                              uint16_t* __restrict__ spk16) {
  const int b = blockIdx.x, q = threadIdx.x;
  float4 c4 = {0, 0, 0, 0};
  if (q < 250) c4 = *(const float4*)(cur1 + (long)b * NH + (q << 2));
  float s0 = 0, s1 = 0, s2 = 0, s3 = 0;
  float m0 = 0, m1 = 0, m2 = 0, m3 = 0;
  float r0 = 0, r1 = 0, r2 = 0, r3 = 0;   // -1.0 if spiked last step
  const float k9 = 0.9f, k85 = 0.85f, n1 = -1.0f;
  uint32_t* sp = spk32 + ((long)b << 8) + q;
  const long gstep = (long)NB << 8;
#define STEP(SH, BUF)                                                       \
  {                                                                         \
    float t0, t1, x0, x1, x2, x3;                                           \
    asm("v_fma_f32 %[s0], %[k9], %[s0], %[c0]\n\t"                          \
        "v_fma_f32 %[s1], %[k9], %[s1], %[c1]\n\t"                          \
        "v_fma_f32 %[s2], %[k9], %[s2], %[c2]\n\t"                          \
        "v_fma_f32 %[s3], %[k9], %[s3], %[c3]\n\t"                          \
        "v_add_f32 %[x0], %[s0], %[r0]\n\t"                                 \
        "v_add_f32 %[x1], %[s1], %[r1]\n\t"                                 \
        "v_add_f32 %[x2], %[s2], %[r2]\n\t"                                 \
        "v_add_f32 %[x3], %[s3], %[r3]\n\t"                                 \
        "v_fma_f32 %[m0], %[k85], %[m0], %[x0]\n\t"                         \
        "v_fma_f32 %[m1], %[k85], %[m1], %[x1]\n\t"                         \
        "v_fma_f32 %[m2], %[k85], %[m2], %[x2]\n\t"                         \
        "v_fma_f32 %[m3], %[k85], %[m3], %[x3]\n\t"                         \
        "v_cmp_lt_f32 vcc, 1.0, %[m0]\n\t"                                  \
        "v_cndmask_b32 %[r0], 0, %[n1], vcc\n\t"                            \
        "v_cmp_lt_f32 vcc, 1.0, %[m1]\n\t"                                  \
        "v_cndmask_b32 %[r1], 0, %[n1], vcc\n\t"                            \
        "v_cmp_lt_f32 vcc, 1.0, %[m2]\n\t"                                  \
        "v_cndmask_b32 %[r2], 0, %[n1], vcc\n\t"                            \
        "v_cmp_lt_f32 vcc, 1.0, %[m3]\n\t"                                  \
        "v_cndmask_b32 %[r3], 0, %[n1], vcc\n\t"                            \
        "v_fma_f32 %[t0], %[r1], -2.0, -%[r0]\n\t"                          \
        "v_fma_f32 %[t1], %[r3], -2.0, -%[r2]\n\t"                          \
        "v_fma_f32 %[t0], %[t1], 4.0, %[t0]\n\t"                            \
        "v_cvt_u32_f32 %[t1], %[t0]\n\t"                                    \
        "v_lshl_or_b32 %[buf], %[t1], " #SH ", %[buf]"                      \
        : [s0] "+v"(s0), [s1] "+v"(s1), [s2] "+v"(s2), [s3] "+v"(s3),       \
          [m0] "+v"(m0), [m1] "+v"(m1), [m2] "+v"(m2), [m3] "+v"(m3),       \
          [r0] "+v"(r0), [r1] "+v"(r1), [r2] "+v"(r2), [r3] "+v"(r3),       \
          [buf] "+v"(BUF), [t0] "=&v"(t0), [t1] "=&v"(t1),                  \
          [x0] "=&v"(x0), [x1] "=&v"(x1), [x2] "=&v"(x2), [x3] "=&v"(x3)    \
        : [c0] "v"(c4.x), [c1] "v"(c4.y), [c2] "v"(c4.z), [c3] "v"(c4.w),   \
          [k9] "v"(k9), [k85] "v"(k85), [n1] "v"(n1)                        \
        : "vcc");                                                           \
  }
  uint32_t bufA = 0, bufB = 0;
  for (int gi = 0; gi < 6; ++gi) {   // 6 x 16 steps = 96
    bufA = 0;
    STEP(0, bufA) STEP(4, bufA) STEP(8, bufA) STEP(12, bufA)
    STEP(16, bufA) STEP(20, bufA) STEP(24, bufA) STEP(28, bufA)
    *sp = bufA;  sp += gstep;
    bufB = 0;
    STEP(0, bufB) STEP(4, bufB) STEP(8, bufB) STEP(12, bufB)
    STEP(16, bufB) STEP(20, bufB) STEP(24, bufB) STEP(28, bufB)
    *sp = bufB;  sp += gstep;
  }
  bufA = 0;
  STEP(0, bufA) STEP(4, bufA) STEP(8, bufA) STEP(12, bufA)
  spk16[((long)b << 8) + q] = (uint16_t)bufA;
#undef STEP
}

// ---------------- K3a: fc2 for groups 0..11 (8 t per wave) -----------------
// k-bijection h = kc*32 + g*8 + j: per kc the wave's 4 g-lanes read 32
// CONTIGUOUS bytes per row, so each row streams sequentially (line fully
// consumed within 4 kc). 16 rows/wave, 6144 waves (6/SIMD), 1-deep prefetch.
__global__ __launch_bounds__(256) void k_fc2a(const uint32_t* __restrict__ spk,
                                              const uint16_t* __restrict__ w2bf,
                                              const float* __restrict__ b2,
                                              float* __restrict__ cur2) {
  const int lane = threadIdx.x & 63, w = threadIdx.x >> 6;
  const int x = lane & 15, g = lane >> 4;
  const int wid = blockIdx.x * 4 + w;       // 0..6143
  const int gq = wid >> 9;                  // group 0..11 (512 wids per gq)
  const int bb = (wid & 511) << 4;          // 16 rows
  const uint16_t* wb = w2bf + (x << 10) + (g << 3);
  const uint32_t* s0 = spk + (((long)gq * NB + bb + x) << 8) + (g << 1);
  f32x4 acc[8];
#pragma unroll
  for (int t = 0; t < 8; ++t) acc[t] = (f32x4){0, 0, 0, 0};

  uint2 d = *(const uint2*)(s0);
#pragma unroll
  for (int kc = 0; kc < 32; ++kc) {
    uint2 dn = *(const uint2*)(s0 + ((kc + 1) << 3));   // prefetch (last lands in ws, unused)
    bf16x8 af = *(const bf16x8*)(wb + (kc << 5));
#pragma unroll
    for (int t = 0; t < 8; ++t) {
      union { uint32_t u[4]; bf16x8 v; } bf;
#pragma unroll
      for (int j = 0; j < 4; ++j) {
        uint32_t src = (j < 2) ? d.x : d.y;
        int pos = 4 * t + 2 * (j & 1);
        uint32_t t2 = (src >> pos) & 3u;
        uint32_t hb = (src >> (pos + 1)) & 1u;
        bf.u[j] = (hb * 0xFFFEu + t2) * 0x3F80u;
      }
      acc[t] = __builtin_amdgcn_mfma_f32_16x16x32_bf16(af, bf.v, acc[t],
                                                       0, 0, 0);
    }
    d = dn;
  }
  float bias[4];
#pragma unroll
  for (int r = 0; r < 4; ++r) {
    int o = (g << 2) + r;
    bias[r] = (o < NOUT) ? b2[o] : 0.0f;
  }
  long row = bb + x;
#pragma unroll
  for (int t = 0; t < 8; ++t) {
    long tb = ((long)(gq * 8 + t) * NB + row) * NOUT;
#pragma unroll
    for (int r = 0; r < 4; ++r) {
      int o = (g << 2) + r;
      if (o < NOUT) cur2[tb + o] = acc[t][r] + bias[r];
    }
  }
}

// ---------------- K3b: fc2 for t=96..99 (u16 tail layout) ------------------
__global__ __launch_bounds__(256) void k_fc2b(const uint32_t* __restrict__ spk16d,
                                              const uint16_t* __restrict__ w2bf,
                                              const float* __restrict__ b2,
                                              float* __restrict__ cur2) {
  const int lane = threadIdx.x & 63, w = threadIdx.x >> 6;
  const int x = lane & 15, g = lane >> 4;
  const int wid = blockIdx.x * 4 + w;       // 0..255
  const int bb = wid << 5;
  const uint16_t* wb = w2bf + (x << 10) + (g << 8);
  const uint32_t* s0 = spk16d + ((long)(bb + x) << 7) + (g << 5);
  const uint32_t* s1 = s0 + (16 << 7);
  f32x4 acc[2][4];
#pragma unroll
  for (int i = 0; i < 2; ++i)
#pragma unroll
    for (int t = 0; t < 4; ++t) acc[i][t] = (f32x4){0, 0, 0, 0};

#pragma unroll 2
  for (int kc = 0; kc < 32; ++kc) {
    bf16x8 af = *(const bf16x8*)(wb + (kc << 3));
    uint32_t d0 = s0[kc];
    uint32_t d1 = s1[kc];
#pragma unroll
    for (int i = 0; i < 2; ++i) {
      uint32_t d = i ? d1 : d0;
#pragma unroll
      for (int t = 0; t < 4; ++t) {
        union { uint32_t u[4]; bf16x8 v; } bf;
#pragma unroll
        for (int j = 0; j < 4; ++j) {
          int pos = 4 * t + 2 * (j & 1) + ((j >> 1) << 4);
          uint32_t t2 = (d >> pos) & 3u;
          uint32_t hb = (d >> (pos + 1)) & 1u;
          bf.u[j] = (hb * 0xFFFEu + t2) * 0x3F80u;
        }
        acc[i][t] = __builtin_amdgcn_mfma_f32_16x16x32_bf16(af, bf.v,
                                                            acc[i][t], 0, 0, 0);
      }
    }
  }
  float bias[4];
#pragma unroll
  for (int r = 0; r < 4; ++r) {
    int o = (g << 2) + r;
    bias[r] = (o < NOUT) ? b2[o] : 0.0f;
  }
#pragma unroll
  for (int i = 0; i < 2; ++i) {
    long row = bb + (i << 4) + x;
#pragma unroll
    for (int t = 0; t < 4; ++t) {
      long tb = ((long)(96 + t) * NB + row) * NOUT;
#pragma unroll
      for (int r = 0; r < 4; ++r) {
        int o = (g << 2) + r;
        if (o < NOUT) cur2[tb + o] = acc[i][t][r] + bias[r];
      }
    }
  }
}

// ---------------- K4: LIF2 scan, 4-deep prefetch ---------------------------
__global__ __launch_bounds__(256) void k_lif2(float* io) {
  const int gid = blockIdx.x * 256 + threadIdx.x;   // < 81920
  float* sp = io + gid;
  float* mm = io + 8192000 + gid;
  float syn = 0.0f, mem = 0.0f;
  float c0 = sp[0], c1 = sp[81920], c2 = sp[2 * 81920], c3 = sp[3 * 81920];
  for (int t = 0; t < NT; t += 4) {
    float n0 = sp[(t + 4) * 81920], n1 = sp[(t + 5) * 81920];
    float n2 = sp[(t + 6) * 81920], n3 = sp[(t + 7) * 81920];
#define L2STEP(TT, CC)                                   \
    {                                                    \
      syn = fmaf(0.9f, syn, CC);                         \
      float r = (mem > 1.0f) ? 1.0f : 0.0f;              \
      mem = fmaf(0.85f, mem, syn) - r;                   \
      sp[(t + TT) * 81920] = (mem > 1.0f) ? 1.0f : 0.0f; \
      mm[(t + TT) * 81920] = mem;                        \
    }
    L2STEP(0, c0) L2STEP(1, c1) L2STEP(2, c2) L2STEP(3, c3)
#undef L2STEP
    c0 = n0; c1 = n1; c2 = n2; c3 = n3;
  }
}

extern "C" void kernel_launch(void* const* d_in, const int* in_sizes, int n_in,
                              void* d_out, int out_size, void* d_ws, size_t ws_size,
                              hipStream_t stream) {
  const float* x  = (const float*)d_in[0];
  const float* W1 = (const float*)d_in[1];
  const float* b1 = (const float*)d_in[2];
  const float* W2 = (const float*)d_in[3];
  const float* b2 = (const float*)d_in[4];
  float* out = (float*)d_out;
  float* memhalf = out + 8192000;                          // cur1 / mem_rec

  uint32_t* spk32 = (uint32_t*)d_ws;                       // 100663296 B
  uint32_t* spk16d = (uint32_t*)((char*)d_ws + 100663296); // 4194304 B
  uint16_t* spk16 = (uint16_t*)spk16d;
  uint16_t* w2bf = (uint16_t*)((char*)d_ws + 104857600);   // 32768 B

  uint16_t* xh = (uint16_t*)d_out;                         // staging in spk half
  uint16_t* xl = (uint16_t*)((char*)d_out + 13107200);
  uint16_t* wh = (uint16_t*)((char*)d_out + 26214400);
  uint16_t* wl = (uint16_t*)((char*)d_out + 27852800);

  k_w2bf<<<64, 256, 0, stream>>>(W2, w2bf);
  k_split<<<25600, 256, 0, stream>>>(x, xh, xl, NB, NB * KP);
  k_split<<<3200, 256, 0, stream>>>(W1, wh, wl, NH, NHP * KP);
  dim3 gg(128, 4);
  k_gemm1m<<<gg, 256, 0, stream>>>(xh, xl, wh, wl, b1, memhalf);
  k_lif1<<<NB, 256, 0, stream>>>(memhalf, spk32, spk16);
  k_fc2a<<<1536, 256, 0, stream>>>(spk32, w2bf, b2, out);
  k_fc2b<<<64, 256, 0, stream>>>(spk16d, w2bf, b2, out);
  k_lif2<<<320, 256, 0, stream>>>(out);
}